// Round 11
// baseline (263.196 us; speedup 1.0000x reference)
//
#include <hip/hip_runtime.h>
#include <cstdint>
#include <cstddef>

typedef unsigned short u16;
typedef __bf16 bfx8 __attribute__((ext_vector_type(8)));
typedef float f32x4 __attribute__((ext_vector_type(4)));

#define NEGV -10000000.0f
constexpr int cB = 32, cN = 512, cD = 128, cF = 20, cL = 5;

__device__ __forceinline__ float bf2f(u16 h){ unsigned u = ((unsigned)h)<<16; return __builtin_bit_cast(float,u); }
__device__ __forceinline__ u16 f2bf(float f){ unsigned u = __builtin_bit_cast(unsigned,f); return (u16)((u + 0x7fffu + ((u>>16)&1u))>>16); }

// ===== canonical weight buffer layout (element offsets, bf16) =====
constexpr int WOF_EMB  = 0;
constexpr int WOF_CEMB = 2560;
constexpr int WOF_AW   = 5120;
constexpr int WOF_CW   = 250880;
constexpr int WOF_WE1  = 496640;
constexpr int WOF_WE2  = 529408;
constexpr int WOF_WB1  = 529536;
constexpr int WOF_WB2  = 562304;
constexpr int WOF_WS1  = 562688;
constexpr int WOF_WS2  = 579072;
constexpr int WOF_WQ1  = 579328;
constexpr int WOF_WQ2  = 612096;
constexpr int WTOTAL   = 612224;

struct WPtrs { const void* p[12]; };

// ================= canonicalize weights to bf16 (self-detecting dtype) =================
__global__ __launch_bounds__(256) void canon_w(WPtrs wp, u16* __restrict__ Wc){
  __shared__ int s_flag;
  int t = threadIdx.x;
  if (t == 0) s_flag = 0;
  __syncthreads();
  const u16* probe = (const u16*)wp.p[2];
  int big = 0;
  #pragma unroll
  for (int i=0;i<2;++i){
    float a = fabsf(bf2f(probe[i*256 + t]));
    if (!(a < 1e10f)) big = 1;
  }
  if (__any(big)) s_flag = 1;       // benign race: only ever sets 1
  __syncthreads();
  int flag = s_flag;
  int i = blockIdx.x*256 + t;
  if (i >= WTOTAL) return;
  constexpr int offs[13] = {WOF_EMB, WOF_CEMB, WOF_AW, WOF_CW, WOF_WE1, WOF_WE2,
                            WOF_WB1, WOF_WB2, WOF_WS1, WOF_WS2, WOF_WQ1, WOF_WQ2, WTOTAL};
  int a = 0;
  #pragma unroll
  for (int k = 1; k < 12; ++k) if (i >= offs[k]) a = k;
  int off = i - offs[a];
  const void* p = wp.p[a];
  Wc[i] = flag ? f2bf(((const float*)p)[off]) : ((const u16*)p)[off];
}

// ================= prep: transpose weights; blk 0..29 GCN W, blk 30 = We1 bottom =================
__global__ __launch_bounds__(256) void prep_w(const u16* __restrict__ Wc, u16* __restrict__ WT){
  __shared__ u16 sh[128*129];
  int blk = blockIdx.x;
  const u16* in;
  if (blk < 30){
    int s = blk/15; int lr = blk%15;
    in = Wc + (s ? WOF_CW : WOF_AW) + (size_t)lr*16384;
  } else {
    in = Wc + WOF_WE1 + 128*cD;           // We1 bottom half [k=128..255][e]
  }
  u16* out = WT + (size_t)blk*16384;
  int t = threadIdx.x;
  #pragma unroll 4
  for (int i=0;i<64;++i){ int idx=i*256+t; int d=idx>>7, e=idx&127; sh[e*129+d]=in[idx]; }
  __syncthreads();
  #pragma unroll 4
  for (int i=0;i<64;++i){ int idx=i*256+t; int e=idx>>7, d=idx&127; out[idx]=sh[e*129+d]; }
}

// ================= emb: h0 = relu(fatoms @ W) bf16, both stacks =================
__global__ __launch_bounds__(128) void emb(const float* __restrict__ fatoms, const u16* __restrict__ Wc, u16* __restrict__ h0){
  int row = blockIdx.x;
  int s = row >> 14; int bn = row & 16383;
  __shared__ float fa[cF];
  int t = threadIdx.x;
  if (t < cF) fa[t] = fatoms[(size_t)bn*cF + t];
  __syncthreads();
  const u16* W = Wc + (s ? WOF_CEMB : WOF_EMB);
  float acc = 0.f;
  #pragma unroll
  for (int f=0; f<cF; ++f) acc += fa[f]*bf2f(W[f*cD + t]);
  h0[((size_t)s*cB*cN + bn)*cD + t] = f2bf(fmaxf(acc,0.f));
}

// ================= MFMA tile helpers (m97 recipe) =================
__device__ __forceinline__ void stage16k(const u16* gbase, int ldaB, int ktB, char* sm, int w, int l){
  #pragma unroll
  for (int i=0;i<4;++i){
    int c = (w<<2) + i;
    int row = (c<<3) + (l>>3);
    const char* src = (const char*)gbase + (size_t)row*ldaB + ktB + (((l&7)^(row&7))<<4);
    __builtin_amdgcn_global_load_lds((const __attribute__((address_space(1))) void*)src,
                                     (__attribute__((address_space(3))) void*)(sm + (c<<10)), 16, 0, 0);
  }
}
__device__ __forceinline__ void stage4k(const u16* gbase, int ldaB, int ktB, char* sm, int w, int l){
  int c = w;                              // 4 chunks of 1KB -> 32 rows
  int row = (c<<3) + (l>>3);
  const char* src = (const char*)gbase + (size_t)row*ldaB + ktB + (((l&7)^(row&7))<<4);
  __builtin_amdgcn_global_load_lds((const __attribute__((address_space(1))) void*)src,
                                   (__attribute__((address_space(3))) void*)(sm + (c<<10)), 16, 0, 0);
}
__device__ __forceinline__ bfx8 readfrag(const char* sm, int row, int kk, int l){
  int col = ((kk<<6) + ((l>>4)<<4)) ^ ((row&7)<<4);
  return *(const bfx8*)(sm + row*128 + col);
}
template<int MF,int NF>
__device__ __forceinline__ void mfma_tile(const char* A, const char* Bm, int ra, int rb, int l, f32x4 (&acc)[MF][NF]){
  #pragma unroll
  for (int kk=0; kk<2; ++kk){
    bfx8 af[MF], bv[NF];
    #pragma unroll
    for (int f=0; f<MF; ++f) af[f] = readfrag(A,  ra+(f<<4)+(l&15), kk, l);
    #pragma unroll
    for (int f=0; f<NF; ++f) bv[f] = readfrag(Bm, rb+(f<<4)+(l&15), kk, l);
    #pragma unroll
    for (int mf=0; mf<MF; ++mf)
      #pragma unroll
      for (int nf=0; nf<NF; ++nf)
        acc[mf][nf] = __builtin_amdgcn_mfma_f32_16x16x32_bf16(af[mf], bv[nf], acc[mf][nf], 0,0,0);
  }
}
// coalesced panel flushes
__device__ __forceinline__ void flush16k(const char* P, char* gbase, int ldB, int colB, int t){
  #pragma unroll
  for (int j=0;j<4;++j){
    int p = j*4096 + t*16;
    int e = p>>7, col = p&127;
    int4 v = *(const int4*)(P + p);
    *(int4*)(gbase + (size_t)e*ldB + colB + col) = v;
  }
}
__device__ __forceinline__ void flush8k(const char* P, char* gbase, int ldB, int colB, int t){
  #pragma unroll
  for (int j=0;j<2;++j){
    int p = j*4096 + t*16;
    int e = p>>6, col = p&63;
    int4 v = *(const int4*)(P + p);
    *(int4*)(gbase + (size_t)e*ldB + colB + col) = v;
  }
}

// ================= K1 (layer 0 only): hw^T = W^T h + b =================
__global__ __launch_bounds__(256,2) void k1_hw(const u16* __restrict__ WT, const u16* __restrict__ h,
                                               const float* __restrict__ actor_b, const float* __restrict__ critic_b,
                                               u16* __restrict__ hwT, int layer){
  __shared__ __align__(16) char smA[16384];
  __shared__ __align__(16) char smB[16384];
  int blk = blockIdx.x;
  int nt = blk & 3; int srb = blk >> 2;
  int s = srb/96; int rb = srb%96; int r = rb>>5; int b = rb&31;
  int t = threadIdx.x, w = t>>6, l = t&63, wr = w>>1, wc = w&1;
  const u16* Abase = WT + (size_t)(s*15 + layer*3 + r)*16384;
  const u16* Bbase = h + ((size_t)s*cB*cN + (size_t)b*cN + (size_t)nt*128)*cD;
  f32x4 acc[4][4];
  #pragma unroll
  for (int i=0;i<4;++i){ acc[i][0]=f32x4{0,0,0,0}; acc[i][1]=f32x4{0,0,0,0}; acc[i][2]=f32x4{0,0,0,0}; acc[i][3]=f32x4{0,0,0,0}; }
  for (int kt=0; kt<2; ++kt){
    __syncthreads();
    stage16k(Abase, 256, kt*128, smA, w, l);
    stage16k(Bbase, 256, kt*128, smB, w, l);
    __syncthreads();
    mfma_tile<4,4>(smA, smB, wr<<6, wc<<6, l, acc);
  }
  const float* bias = (s ? critic_b : actor_b) + (layer*3 + r)*cD;
  __syncthreads();                       // all waves done reading smA/smB
  char* OPh = wc ? smB : smA;
  #pragma unroll
  for (int mf=0; mf<4; ++mf)
    #pragma unroll
    for (int nf=0; nf<4; ++nf)
      #pragma unroll
      for (int j=0; j<4; ++j){
        int e  = (wr<<6) + (mf<<4) + ((l>>4)<<2) + j;
        int mh = (nf<<4) + (l&15);
        *(u16*)(OPh + e*128 + mh*2) = f2bf(acc[mf][nf][j] + bias[e]);
      }
  __syncthreads();
  char* outB = (char*)(hwT + (size_t)((s*3+r)*cB + b)*cD*cN);
  flush16k(smA, outB, 1024, nt*256 + 0,   t);
  flush16k(smB, outB, 1024, nt*256 + 128, t);
}

// ================= K2F layer 0: 64x128 tiles, 512 blocks, adj-direct pipeline (R10, verified) =================
__global__ __launch_bounds__(256,2) void k2f_l0(const float* __restrict__ adj, u16* __restrict__ adjT,
                                                const u16* __restrict__ hwT_in, u16* __restrict__ hwT_out,
                                                const float* __restrict__ all_mask, const u16* __restrict__ WT,
                                                const float* __restrict__ actor_b, const float* __restrict__ critic_b){
  __shared__ __align__(16) char pool[73728];
  int blk = blockIdx.x;                          // 512 blocks
  int xcd = blk & 7; int slot = blk >> 3;
  int b = (slot>>4)*8 + xcd;
  int rest = slot & 15; int s = rest>>3; int mt = rest&7;
  int t = threadIdx.x, w = t>>6, l = t&63, wr = w>>1, wc = w&1;
  const u16* hwB = hwT_in + (size_t)(s*3*cB + b)*cD*cN;
  const size_t hwRs = (size_t)cB*cD*cN;
  f32x4 sum[2][4];
  #pragma unroll
  for (int i=0;i<2;++i)
    #pragma unroll
    for (int j=0;j<4;++j) sum[i][j]=f32x4{0,0,0,0};

  f32x4 a3[3][2][4];
  #pragma unroll
  for (int r=0;r<3;++r)
    #pragma unroll
    for (int i=0;i<2;++i)
      #pragma unroll
      for (int j=0;j<4;++j) a3[r][i][j]=f32x4{0,0,0,0};
  const int nl  = t>>2;
  const int m8  = (t&3)*2;
  const float* asrc = adj + ((size_t)(b*cN + mt*64 + nl)*cN + m8*8)*3;
  float4 v[12];
  #pragma unroll
  for (int q=0;q<12;++q) v[q] = ((const float4*)asrc)[q];      // prologue: kt=0
  for (int kt=0; kt<8; ++kt){
    __builtin_amdgcn_s_barrier();
    __builtin_amdgcn_sched_barrier(0);
    stage16k(hwB,        1024, kt*128, pool+24576, w, l);
    stage16k(hwB+hwRs,   1024, kt*128, pool+40960, w, l);
    stage16k(hwB+2*hwRs, 1024, kt*128, pool+57344, w, l);
    __builtin_amdgcn_sched_barrier(0);
    const float* vf = (const float*)v;
    __align__(16) u16 o[2][3][8];
    #pragma unroll
    for (int i=0;i<2;++i)
      #pragma unroll
      for (int r=0;r<3;++r)
        #pragma unroll
        for (int k=0;k<8;++k) o[i][r][k] = f2bf(vf[i*24 + k*3 + r]);
    #pragma unroll
    for (int i=0;i<2;++i){
      int m8i = m8 + i;
      #pragma unroll
      for (int r=0;r<3;++r)
        *(int4*)(pool + r*8192 + nl*128 + ((m8i*16) ^ ((nl&7)<<4))) = *(const int4*)&o[i][r][0];
    }
    if (kt < 7){
      const float* sp = asrc + (size_t)(kt+1)*64*3;
      #pragma unroll
      for (int q=0;q<12;++q) v[q] = ((const float4*)sp)[q];
    }
    __builtin_amdgcn_sched_barrier(0);
    if (kt < 7) asm volatile("s_waitcnt vmcnt(12)" ::: "memory");
    else        asm volatile("s_waitcnt vmcnt(0)"  ::: "memory");
    asm volatile("s_waitcnt lgkmcnt(0)" ::: "memory");
    __builtin_amdgcn_sched_barrier(0);
    __builtin_amdgcn_s_barrier();
    __builtin_amdgcn_sched_barrier(0);
    if (s == 0){
      #pragma unroll
      for (int r=0;r<3;++r){
        char* gb = (char*)adjT + (((size_t)(r*cB + b)*cN + (size_t)mt*64)*cN + (size_t)kt*64)*2;
        #pragma unroll
        for (int j=0;j<2;++j){
          int p = j*4096 + t*16;
          int n2 = p>>7, chunk = p&127;
          int4 val = *(const int4*)(pool + r*8192 + n2*128 + (chunk ^ ((n2&7)<<4)));
          *(int4*)(gb + (size_t)n2*1024 + chunk) = val;
        }
      }
    }
    #pragma unroll
    for (int r=0;r<3;++r)
      mfma_tile<2,4>(pool + r*8192, pool + 24576 + r*16384, wr<<5, wc<<6, l, a3[r]);
  }
  #pragma unroll
  for (int r=0;r<3;++r)
    #pragma unroll
    for (int mf=0;mf<2;++mf)
      #pragma unroll
      for (int nf=0;nf<4;++nf)
        #pragma unroll
        for (int j=0;j<4;++j)
          sum[mf][nf][j] += fmaxf(a3[r][mf][nf][j], 0.f);
  __syncthreads();
  char* hT0 = pool;
  char* hT1 = pool + 8192;
  char* OP  = pool + 57344;
  #pragma unroll
  for (int mf=0; mf<2; ++mf)
    #pragma unroll
    for (int nf=0; nf<4; ++nf)
      #pragma unroll
      for (int j=0; j<4; ++j){
        int nloc = (wr<<5) + (mf<<4) + ((l>>4)<<2) + j;
        int e    = (wc<<6) + (nf<<4) + (l&15);
        int n    = mt*64 + nloc;
        u16 hv = f2bf(sum[mf][nf][j] * all_mask[b*cN + n]);
        char* base = (e & 64) ? hT1 : hT0;
        *(u16*)(base + nloc*128 + (((e&63)*2) ^ ((nloc&7)<<4))) = hv;
      }
  char* W0 = pool + 24576;
  char* W1 = W0 + 16384;
  for (int r=0; r<3; ++r){
    __syncthreads();
    const u16* Wbase = WT + (size_t)(s*15 + 1*3 + r)*16384;       // layer+1 = 1
    stage16k(Wbase, 256, 0,   W0, w, l);
    stage16k(Wbase, 256, 128, W1, w, l);
    __syncthreads();
    f32x4 acc2[4][2];
    #pragma unroll
    for (int i=0;i<4;++i){ acc2[i][0]=f32x4{0,0,0,0}; acc2[i][1]=f32x4{0,0,0,0}; }
    mfma_tile<4,2>(W0, hT0, wr<<6, wc<<5, l, acc2);
    mfma_tile<4,2>(W1, hT1, wr<<6, wc<<5, l, acc2);
    const float* bias = (s ? critic_b : actor_b) + (1*3 + r)*cD;
    #pragma unroll
    for (int mf=0; mf<4; ++mf)
      #pragma unroll
      for (int nf=0; nf<2; ++nf)
        #pragma unroll
        for (int j=0; j<4; ++j){
          int e   = (wr<<6) + (mf<<4) + ((l>>4)<<2) + j;
          int m64 = (wc<<5) + (nf<<4) + (l&15);
          *(u16*)(OP + e*128 + m64*2) = f2bf(acc2[mf][nf][j] + bias[e]);
        }
    __syncthreads();
    char* outB = (char*)(hwT_out + (size_t)((s*3+r)*cB + b)*cD*cN);
    flush16k(OP, outB, 1024, mt*128, t);
  }
}

// ================= K2F layers 1..4: 32x128 tiles, 1024 blocks = 4/CU =================
__global__ __launch_bounds__(256,4) void k2f_ln(const u16* __restrict__ adjT,
                                                const u16* __restrict__ hwT_in, u16* __restrict__ hwT_out,
                                                const float* __restrict__ all_mask, const u16* __restrict__ WT,
                                                const float* __restrict__ actor_b, const float* __restrict__ critic_b,
                                                u16* __restrict__ hfin, int layer){
  __shared__ __align__(16) char pool[28672];     // 28 KB: 4 blocks/CU (VGPR-capped)
  int blk = blockIdx.x;                          // 1024 blocks
  int xcd = blk & 7; int slot = blk >> 3;        // all 32 (s,mt) of one b on one XCD
  int b = (slot>>5)*8 + xcd;
  int rest = slot & 31; int s = rest>>4; int mt = rest&15;
  int t = threadIdx.x, w = t>>6, l = t&63, wr = w>>1, wc = w&1;
  const u16* hwB = hwT_in + (size_t)(s*3*cB + b)*cD*cN;
  const size_t hwRs = (size_t)cB*cD*cN;
  const u16* adjB = adjT + ((size_t)b*cN + (size_t)mt*32)*cN;
  const size_t adjRs = (size_t)cB*cN*cN;
  f32x4 sum[1][4];
  #pragma unroll
  for (int j=0;j<4;++j) sum[0][j]=f32x4{0,0,0,0};
  // main: smA@0 (4K: 32n x 64m), smB@4096 (16K: 128e x 64m)
  for (int r=0;r<3;++r){
    f32x4 acc[1][4];
    #pragma unroll
    for (int j=0;j<4;++j) acc[0][j]=f32x4{0,0,0,0};
    for (int kt=0;kt<8;++kt){
      __syncthreads();
      stage4k (adjB + (size_t)r*adjRs, 1024, kt*128, pool, w, l);
      stage16k(hwB  + (size_t)r*hwRs,  1024, kt*128, pool+4096, w, l);
      __syncthreads();
      mfma_tile<1,4>(pool, pool+4096, wr<<4, wc<<6, l, acc);
    }
    #pragma unroll
    for (int nf=0;nf<4;++nf)
      #pragma unroll
      for (int j=0;j<4;++j)
        sum[0][nf][j] += fmaxf(acc[0][nf][j], 0.f);
  }
  __syncthreads();                     // main-loop LDS reads done
  char* hT0 = pool + 20480;            // 32 m-rows x 64 d (4K each)
  char* hT1 = pool + 24576;
  #pragma unroll
  for (int nf=0; nf<4; ++nf)
    #pragma unroll
    for (int j=0; j<4; ++j){
      int nloc = (wr<<4) + ((l>>4)<<2) + j;                // local n row (0..31)
      int e    = (wc<<6) + (nf<<4) + (l&15);               // d col (0..127)
      int n    = mt*32 + nloc;
      u16 hv = f2bf(sum[0][nf][j] * all_mask[b*cN + n]);
      char* base = (e & 64) ? hT1 : hT0;
      *(u16*)(base + nloc*128 + (((e&63)*2) ^ ((nloc&7)<<4))) = hv;
    }
  if (layer == cL-1){
    __syncthreads();                   // hT panels complete
    char* gdst = (char*)(hfin + ((size_t)(s*cB + b)*cN + (size_t)mt*32)*cD);
    #pragma unroll
    for (int j=0;j<2;++j){
      int p = j*4096 + t*16;
      int nloc = p>>8, ebyte = p&255;
      char* hbase = (ebyte & 128) ? hT1 : hT0;
      int chunk = ebyte & 127;
      int4 v2 = *(const int4*)(hbase + nloc*128 + (chunk ^ ((nloc&7)<<4)));
      *(int4*)(gdst + (size_t)nloc*256 + ebyte) = v2;
    }
    return;
  }
  // fused next-layer k1: W halves time-share pool+0 (16K); OP at pool+0 (8K)
  for (int r=0; r<3; ++r){
    __syncthreads();                                 // hT visible / prev OP flush reads done
    const u16* Wbase = WT + (size_t)(s*15 + (layer+1)*3 + r)*16384;
    stage16k(Wbase, 256, 0, pool, w, l);             // W rows e, d 0..63
    __syncthreads();
    f32x4 acc2[4][1];
    #pragma unroll
    for (int i=0;i<4;++i) acc2[i][0]=f32x4{0,0,0,0};
    mfma_tile<4,1>(pool, hT0, wr<<6, wc<<4, l, acc2);
    __syncthreads();                                 // W0 reads done
    stage16k(Wbase, 256, 128, pool, w, l);           // W rows e, d 64..127
    __syncthreads();
    mfma_tile<4,1>(pool, hT1, wr<<6, wc<<4, l, acc2);
    __syncthreads();                                 // W1 reads done
    const float* bias = (s ? critic_b : actor_b) + ((layer+1)*3 + r)*cD;
    #pragma unroll
    for (int mf=0; mf<4; ++mf)
      #pragma unroll
      for (int j=0; j<4; ++j){
        int e   = (wr<<6) + (mf<<4) + ((l>>4)<<2) + j;
        int m32 = (wc<<4) + (l&15);
        *(u16*)(pool + e*64 + m32*2) = f2bf(acc2[mf][0][j] + bias[e]);
      }
    __syncthreads();                                 // OP complete
    char* outB = (char*)(hwT_out + (size_t)((s*3+r)*cB + b)*cD*cN);
    flush8k(pool, outB, 1024, mt*64, t);
  }
}

// ================= pooling stage 1: partial sum/max over 32-row chunks =================
__global__ __launch_bounds__(256) void pool_part(const u16* __restrict__ xc, const float* __restrict__ cmask,
                                                 float* __restrict__ part){
  int blk = blockIdx.x;               // b*16 + c
  int b = blk >> 4, c = blk & 15;
  int t = threadIdx.x; int d = t & 127, nh = t >> 7;
  const u16* x = xc + ((size_t)b*cN + c*32 + nh*16)*cD;
  const float* cm = cmask + (size_t)b*cN + c*32 + nh*16;
  float sm = 0.f, mx = -3e38f;
  #pragma unroll
  for (int i=0;i<16;++i){
    float v = bf2f(x[(size_t)i*cD + d]);
    float m = cm[i];
    sm += v*m;
    mx = fmaxf(mx, v + (m==1.0f ? 0.f : NEGV));
  }
  __shared__ float s_sm[2][128], s_mx[2][128];
  s_sm[nh][d] = sm; s_mx[nh][d] = mx;
  __syncthreads();
  if (nh == 0){
    float* dst = part + ((size_t)b*16 + c)*256;
    dst[d]       = sm + s_sm[1][d];
    dst[128 + d] = fmaxf(mx, s_mx[1][d]);
  }
}

// ================= actor: end logits as MFMA GEMM (computes sc internally) =================
__global__ __launch_bounds__(256,2) void end_logits2(const u16* __restrict__ xa, const u16* __restrict__ WT,
                                                     const u16* __restrict__ Wc, const int* __restrict__ focus,
                                                     const float* __restrict__ be1,
                                                     const float* __restrict__ prob_mask, float* __restrict__ logits){
  __shared__ __align__(16) char smA[16384];
  __shared__ __align__(16) char smB[16384];
  __shared__ float s_start[128], sh_sc[128], sh_w2[128], rowsum[2][128];
  int blk = blockIdx.x;                // b*4 + nt
  int nt = blk & 3, b = blk >> 2;
  int t = threadIdx.x, w = t>>6, l = t&63, wr = w>>1, wc = w&1;
  if (t < 128){
    s_start[t] = bf2f(xa[((size_t)b*cN + focus[b])*cD + t]);
    sh_w2[t]   = bf2f(Wc[WOF_WE2 + t]);
  }
  __syncthreads();
  if (t < 128){
    float a = be1[t];
    #pragma unroll 4
    for (int k=0;k<128;++k) a += s_start[k]*bf2f(Wc[WOF_WE1 + k*cD + t]);
    sh_sc[t] = a;
  }
  const u16* Abase = xa + ((size_t)b*cN + (size_t)nt*128)*cD;
  const u16* Bbase = WT + (size_t)30*16384;
  f32x4 acc[4][4];
  #pragma unroll
  for (int i=0;i<4;++i){ acc[i][0]=f32x4{0,0,0,0}; acc[i][1]=f32x4{0,0,0,0}; acc[i][2]=f32x4{0,0,0,0}; acc[i][3]=f32x4{0,0,0,0}; }
  for (int kt=0; kt<2; ++kt){
    __syncthreads();
    stage16k(Abase, 256, kt*128, smA, w, l);
    stage16k(Bbase, 256, kt*128, smB, w, l);
    __syncthreads();
    mfma_tile<4,4>(smA, smB, wr<<6, wc<<6, l, acc);
  }
  float p[4][4];
  #pragma unroll
  for (int mf=0;mf<4;++mf)
    #pragma unroll
    for (int j=0;j<4;++j) p[mf][j] = 0.f;
  #pragma unroll
  for (int mf=0; mf<4; ++mf)
    #pragma unroll
    for (int nf=0; nf<4; ++nf){
      int e = (wc<<6) + (nf<<4) + (l&15);
      float scv = sh_sc[e], w2 = sh_w2[e];
      #pragma unroll
      for (int j=0; j<4; ++j)
        p[mf][j] += fmaxf(acc[mf][nf][j] + scv, 0.f) * w2;
    }
  #pragma unroll
  for (int mf=0; mf<4; ++mf)
    #pragma unroll
    for (int j=0; j<4; ++j){
      float v = p[mf][j];
      #pragma unroll
      for (int o=1;o<16;o<<=1) v += __shfl_xor(v, o, 64);
      if ((l&15)==0) rowsum[wc][(wr<<6) + (mf<<4) + ((l>>4)<<2) + j] = v;
    }
  __syncthreads();
  if (t < 128){
    int n = nt*128 + t;
    float pm = (prob_mask[b*cN + n]==1.0f) ? 0.f : NEGV;
    logits[b*cN + n] = rowsum[0][t] + rowsum[1][t] + pm;
  }
}

// ================= fused final heads: qvalue + end softmax/entropy + bond/stop =================
__global__ __launch_bounds__(128) void heads_final(const float* __restrict__ part, const u16* __restrict__ Wc,
                                                   const float* __restrict__ bq1, const float* __restrict__ bq2,
                                                   const float* __restrict__ logits, const int* __restrict__ action,
                                                   const u16* __restrict__ xa, const int* __restrict__ focus,
                                                   const float* __restrict__ bb1, const float* __restrict__ bs1,
                                                   float* __restrict__ out){
  int b = blockIdx.x, t = threadIdx.x;
  __shared__ float qin[256];
  __shared__ float sv[128], ev[128];
  __shared__ float redq[2], red5[5][2];
  __shared__ float HendSh;
  sv[t] = bf2f(xa[((size_t)b*cN + focus[b])*cD + t]);
  ev[t] = bf2f(xa[((size_t)b*cN + action[b*3])*cD + t]);
  float sm = 0.f, mx = -3e38f;
  #pragma unroll
  for (int c=0;c<16;++c){
    const float* src = part + ((size_t)b*16 + c)*256;
    sm += src[t];
    mx = fmaxf(mx, src[128 + t]);
  }
  qin[t] = sm; qin[128+t] = mx;
  __syncthreads();
  float acc = bq1[t];
  #pragma unroll 4
  for (int k=0; k<256; ++k) acc += qin[k]*bf2f(Wc[WOF_WQ1 + k*cD + t]);
  float hc = fmaxf(acc,0.f)*bf2f(Wc[WOF_WQ2 + t]);
  #pragma unroll
  for (int o=32;o>0;o>>=1) hc += __shfl_down(hc, o, 64);
  if ((t&63)==0) redq[t>>6] = hc;
  if (t < 64){
    float v[8];
    #pragma unroll
    for (int i=0;i<8;++i) v[i] = logits[b*cN + i*64 + t];
    float m = v[0];
    #pragma unroll
    for (int i=1;i<8;++i) m = fmaxf(m, v[i]);
    #pragma unroll
    for (int o=32;o>0;o>>=1) m = fmaxf(m, __shfl_xor(m, o, 64));
    float e[8]; float s = 0.f;
    #pragma unroll
    for (int i=0;i<8;++i){ e[i] = expf(v[i]-m); s += e[i]; }
    #pragma unroll
    for (int o=32;o>0;o>>=1) s += __shfl_xor(s, o, 64);
    float lns = logf(s);
    float pl = 0.f;
    #pragma unroll
    for (int i=0;i<8;++i){ float p = e[i]/s; pl += p*((v[i]-m) - lns); }
    #pragma unroll
    for (int o=32;o>0;o>>=1) pl += __shfl_xor(pl, o, 64);
    int idx = action[b*3 + 0];
    if (t == (idx & 63)){
      float pe = 0.f;
      #pragma unroll
      for (int i=0;i<8;++i) if ((idx>>6)==i) pe = e[i];
      out[b*3 + 0] = pe / s;
    }
    if (t == 0) HendSh = -pl;
  }
  __syncthreads();
  float ab = bb1[t], as_ = bs1[t];
  #pragma unroll 4
  for (int k=0;k<128;++k){ float svk = sv[k]; ab += svk*bf2f(Wc[WOF_WB1 + k*cD + t]); as_ += svk*bf2f(Wc[WOF_WS1 + k*cD + t]); }
  #pragma unroll 4
  for (int k=0;k<128;++k) ab += ev[k]*bf2f(Wc[WOF_WB1 + (128+k)*cD + t]);
  float hb = fmaxf(ab,0.f), hs = fmaxf(as_,0.f);
  float r0 = hb*bf2f(Wc[WOF_WB2 + t*3+0]);
  float r1 = hb*bf2f(Wc[WOF_WB2 + t*3+1]);
  float r2 = hb*bf2f(Wc[WOF_WB2 + t*3+2]);
  float r3 = hs*bf2f(Wc[WOF_WS2 + t*2+0]);
  float r4 = hs*bf2f(Wc[WOF_WS2 + t*2+1]);
  #pragma unroll
  for (int o=32;o>0;o>>=1){
    r0 += __shfl_xor(r0,o,64); r1 += __shfl_xor(r1,o,64); r2 += __shfl_xor(r2,o,64);
    r3 += __shfl_xor(r3,o,64); r4 += __shfl_xor(r4,o,64);
  }
  if ((t&63)==0){ int wid=t>>6; red5[0][wid]=r0; red5[1][wid]=r1; red5[2][wid]=r2; red5[3][wid]=r3; red5[4][wid]=r4; }
  __syncthreads();
  if (t==0){
    out[128 + b] = redq[0] + redq[1] + bq2[0];
    auto xlx = [](float p){ return p > 0.f ? p*logf(p) : 0.f; };
    float bl0=red5[0][0]+red5[0][1], bl1=red5[1][0]+red5[1][1], bl2=red5[2][0]+red5[2][1];
    float sl0=red5[3][0]+red5[3][1], sl1=red5[4][0]+red5[4][1];
    float m = fmaxf(fmaxf(bl0,bl1),bl2);
    float e0=expf(bl0-m), e1=expf(bl1-m), e2=expf(bl2-m); float S=e0+e1+e2;
    float p0=e0/S, p1=e1/S, p2=e2/S;
    float Hb = -(xlx(p0) + xlx(p1) + xlx(p2));
    int a1 = action[b*3+1];
    out[b*3+1] = (a1==0)?p0:((a1==1)?p1:p2);
    float ms = fmaxf(sl0,sl1);
    float f0=expf(sl0-ms), f1=expf(sl1-ms); float T=f0+f1;
    float q0=f0/T, q1=f1/T;
    float Hs = -(xlx(q0) + xlx(q1));
    int a2 = action[b*3+2];
    out[b*3+2] = (a2==0)?q0:q1;
    out[96+b] = HendSh + Hb + Hs;
  }
}

// ================= launcher =================
extern "C" void kernel_launch(void* const* d_in, const int* in_sizes, int n_in,
                              void* d_out, int out_size, void* d_ws, size_t ws_size,
                              hipStream_t stream){
  const float* fatoms      = (const float*)d_in[0];
  const float* adj         = (const float*)d_in[1];
  const float* all_mask    = (const float*)d_in[2];
  const float* current_mask= (const float*)d_in[3];
  const float* prob_mask   = (const float*)d_in[4];
  const int*   focus       = (const int*)d_in[5];
  const int*   action      = (const int*)d_in[6];
  const float* actor_b     = (const float*)d_in[10];
  const float* critic_b    = (const float*)d_in[12];
  const float* be1         = (const float*)d_in[14];
  const float* bb1         = (const float*)d_in[17];
  const float* bs1         = (const float*)d_in[20];
  const float* bq1         = (const float*)d_in[23];
  const float* bq2         = (const float*)d_in[25];

  char* ws = (char*)d_ws;
  size_t o = 0;
  u16* adjT = (u16*)(ws + o);  o += (size_t)3*cB*cN*cN*2;        // 50.3 MB (written by k2f_l0)
  u16* WT   = (u16*)(ws + o);  o += (size_t)31*16384*2;          //  1.0 MB
  u16* hbuf = (u16*)(ws + o);  o += (size_t)2*2*cB*cN*cD*2;      // 16.8 MB (phase0=h0, phase1=hfin)
  u16* hwT0 = (u16*)(ws + o);  o += (size_t)2*3*cB*cD*cN*2;      // 25.2 MB
  u16* hwT1 = (u16*)(ws + o);  o += (size_t)2*3*cB*cD*cN*2;      // 25.2 MB
  u16* Wcan = (u16*)(ws + o);  o += (size_t)WTOTAL*2;
  float* part   = (float*)(ws + o); o += (size_t)cB*16*256*4;
  float* logits = (float*)(ws + o); o += (size_t)cB*cN*4;
  float* out = (float*)d_out;

  WPtrs wp;
  wp.p[0]=d_in[7];  wp.p[1]=d_in[8];  wp.p[2]=d_in[9];  wp.p[3]=d_in[11];
  wp.p[4]=d_in[13]; wp.p[5]=d_in[15]; wp.p[6]=d_in[16]; wp.p[7]=d_in[18];
  wp.p[8]=d_in[19]; wp.p[9]=d_in[21]; wp.p[10]=d_in[22]; wp.p[11]=d_in[24];

  canon_w<<<dim3((WTOTAL+255)/256), dim3(256), 0, stream>>>(wp, Wcan);
  prep_w<<<dim3(31), dim3(256), 0, stream>>>(Wcan, WT);
  emb<<<dim3(2*cB*cN), dim3(128), 0, stream>>>(fatoms, Wcan, hbuf);

  const size_t hstride = (size_t)2*cB*cN*cD;
  u16* hfin = hbuf + hstride;
  k1_hw<<<dim3(768), dim3(256), 0, stream>>>(WT, hbuf, actor_b, critic_b, hwT0, 0);
  k2f_l0<<<dim3(512), dim3(256), 0, stream>>>(adj, adjT, hwT0, hwT1, all_mask, WT, actor_b, critic_b);
  for (int l=1; l<cL; ++l){
    u16* win  = (l&1) ? hwT1 : hwT0;
    u16* wout = (l&1) ? hwT0 : hwT1;
    k2f_ln<<<dim3(1024), dim3(256), 0, stream>>>(adjT, win, wout, all_mask, WT, actor_b, critic_b, hfin, l);
  }
  const u16* xa = hfin;
  const u16* xc = hfin + (size_t)cB*cN*cD;

  end_logits2<<<dim3(cB*4), dim3(256), 0, stream>>>(xa, WT, Wcan, focus, be1, prob_mask, logits);
  pool_part<<<dim3(cB*16), dim3(256), 0, stream>>>(xc, current_mask, part);
  heads_final<<<dim3(cB), dim3(128), 0, stream>>>(part, Wcan, bq1, bq2, logits, action, xa, focus, bb1, bs1, out);
}

// Round 12
// 256.106 us; speedup vs baseline: 1.0277x; 1.0277x over previous
//
#include <hip/hip_runtime.h>
#include <cstdint>
#include <cstddef>

typedef unsigned short u16;
typedef __bf16 bfx8 __attribute__((ext_vector_type(8)));
typedef float f32x4 __attribute__((ext_vector_type(4)));

#define NEGV -10000000.0f
constexpr int cB = 32, cN = 512, cD = 128, cF = 20, cL = 5;

__device__ __forceinline__ float bf2f(u16 h){ unsigned u = ((unsigned)h)<<16; return __builtin_bit_cast(float,u); }
__device__ __forceinline__ u16 f2bf(float f){ unsigned u = __builtin_bit_cast(unsigned,f); return (u16)((u + 0x7fffu + ((u>>16)&1u))>>16); }

// ===== canonical weight buffer layout (element offsets, bf16) =====
constexpr int WOF_EMB  = 0;
constexpr int WOF_CEMB = 2560;
constexpr int WOF_AW   = 5120;
constexpr int WOF_CW   = 250880;
constexpr int WOF_WE1  = 496640;
constexpr int WOF_WE2  = 529408;
constexpr int WOF_WB1  = 529536;
constexpr int WOF_WB2  = 562304;
constexpr int WOF_WS1  = 562688;
constexpr int WOF_WS2  = 579072;
constexpr int WOF_WQ1  = 579328;
constexpr int WOF_WQ2  = 612096;
constexpr int WTOTAL   = 612224;

struct WPtrs { const void* p[12]; };

// ================= canonicalize weights to bf16 (self-detecting dtype) =================
__global__ __launch_bounds__(256) void canon_w(WPtrs wp, u16* __restrict__ Wc){
  __shared__ int s_flag;
  int t = threadIdx.x;
  if (t == 0) s_flag = 0;
  __syncthreads();
  const u16* probe = (const u16*)wp.p[2];
  int big = 0;
  #pragma unroll
  for (int i=0;i<2;++i){
    float a = fabsf(bf2f(probe[i*256 + t]));
    if (!(a < 1e10f)) big = 1;
  }
  if (__any(big)) s_flag = 1;       // benign race: only ever sets 1
  __syncthreads();
  int flag = s_flag;
  int i = blockIdx.x*256 + t;
  if (i >= WTOTAL) return;
  constexpr int offs[13] = {WOF_EMB, WOF_CEMB, WOF_AW, WOF_CW, WOF_WE1, WOF_WE2,
                            WOF_WB1, WOF_WB2, WOF_WS1, WOF_WS2, WOF_WQ1, WOF_WQ2, WTOTAL};
  int a = 0;
  #pragma unroll
  for (int k = 1; k < 12; ++k) if (i >= offs[k]) a = k;
  int off = i - offs[a];
  const void* p = wp.p[a];
  Wc[i] = flag ? f2bf(((const float*)p)[off]) : ((const u16*)p)[off];
}

// ================= prep: transpose weights; blk 0..29 GCN W, blk 30 = We1 bottom =================
__global__ __launch_bounds__(256) void prep_w(const u16* __restrict__ Wc, u16* __restrict__ WT){
  __shared__ u16 sh[128*129];
  int blk = blockIdx.x;
  const u16* in;
  if (blk < 30){
    int s = blk/15; int lr = blk%15;
    in = Wc + (s ? WOF_CW : WOF_AW) + (size_t)lr*16384;
  } else {
    in = Wc + WOF_WE1 + 128*cD;           // We1 bottom half [k=128..255][e]
  }
  u16* out = WT + (size_t)blk*16384;
  int t = threadIdx.x;
  #pragma unroll 4
  for (int i=0;i<64;++i){ int idx=i*256+t; int d=idx>>7, e=idx&127; sh[e*129+d]=in[idx]; }
  __syncthreads();
  #pragma unroll 4
  for (int i=0;i<64;++i){ int idx=i*256+t; int e=idx>>7, d=idx&127; out[idx]=sh[e*129+d]; }
}

// ================= emb: h0 = relu(fatoms @ W) bf16, both stacks =================
__global__ __launch_bounds__(128) void emb(const float* __restrict__ fatoms, const u16* __restrict__ Wc, u16* __restrict__ h0){
  int row = blockIdx.x;
  int s = row >> 14; int bn = row & 16383;
  __shared__ float fa[cF];
  int t = threadIdx.x;
  if (t < cF) fa[t] = fatoms[(size_t)bn*cF + t];
  __syncthreads();
  const u16* W = Wc + (s ? WOF_CEMB : WOF_EMB);
  float acc = 0.f;
  #pragma unroll
  for (int f=0; f<cF; ++f) acc += fa[f]*bf2f(W[f*cD + t]);
  h0[((size_t)s*cB*cN + bn)*cD + t] = f2bf(fmaxf(acc,0.f));
}

// ================= MFMA tile helpers (m97 recipe) =================
__device__ __forceinline__ void stage16k(const u16* gbase, int ldaB, int ktB, char* sm, int w, int l){
  #pragma unroll
  for (int i=0;i<4;++i){
    int c = (w<<2) + i;
    int row = (c<<3) + (l>>3);
    const char* src = (const char*)gbase + (size_t)row*ldaB + ktB + (((l&7)^(row&7))<<4);
    __builtin_amdgcn_global_load_lds((const __attribute__((address_space(1))) void*)src,
                                     (__attribute__((address_space(3))) void*)(sm + (c<<10)), 16, 0, 0);
  }
}
__device__ __forceinline__ void stage8k(const u16* gbase, int ldaB, int ktB, char* sm, int w, int l){
  #pragma unroll
  for (int i=0;i<2;++i){
    int c = (w<<1) + i;
    int row = (c<<3) + (l>>3);
    const char* src = (const char*)gbase + (size_t)row*ldaB + ktB + (((l&7)^(row&7))<<4);
    __builtin_amdgcn_global_load_lds((const __attribute__((address_space(1))) void*)src,
                                     (__attribute__((address_space(3))) void*)(sm + (c<<10)), 16, 0, 0);
  }
}
__device__ __forceinline__ bfx8 readfrag(const char* sm, int row, int kk, int l){
  int col = ((kk<<6) + ((l>>4)<<4)) ^ ((row&7)<<4);
  return *(const bfx8*)(sm + row*128 + col);
}
template<int MF,int NF>
__device__ __forceinline__ void mfma_tile(const char* A, const char* Bm, int ra, int rb, int l, f32x4 (&acc)[MF][NF]){
  #pragma unroll
  for (int kk=0; kk<2; ++kk){
    bfx8 af[MF], bv[NF];
    #pragma unroll
    for (int f=0; f<MF; ++f) af[f] = readfrag(A,  ra+(f<<4)+(l&15), kk, l);
    #pragma unroll
    for (int f=0; f<NF; ++f) bv[f] = readfrag(Bm, rb+(f<<4)+(l&15), kk, l);
    #pragma unroll
    for (int mf=0; mf<MF; ++mf)
      #pragma unroll
      for (int nf=0; nf<NF; ++nf)
        acc[mf][nf] = __builtin_amdgcn_mfma_f32_16x16x32_bf16(af[mf], bv[nf], acc[mf][nf], 0,0,0);
  }
}
// coalesced panel flush: 16KB LDS panel [128 rows][128B] -> global rows
__device__ __forceinline__ void flush16k(const char* P, char* gbase, int ldB, int colB, int t){
  #pragma unroll
  for (int j=0;j<4;++j){
    int p = j*4096 + t*16;
    int e = p>>7, col = p&127;
    int4 v = *(const int4*)(P + p);
    *(int4*)(gbase + (size_t)e*ldB + colB + col) = v;
  }
}

// ================= K1 (layer 0 only): hw^T = W^T h + b =================
__global__ __launch_bounds__(256,2) void k1_hw(const u16* __restrict__ WT, const u16* __restrict__ h,
                                               const float* __restrict__ actor_b, const float* __restrict__ critic_b,
                                               u16* __restrict__ hwT, int layer){
  __shared__ __align__(16) char smA[16384];
  __shared__ __align__(16) char smB[16384];
  int blk = blockIdx.x;
  int nt = blk & 3; int srb = blk >> 2;
  int s = srb/96; int rb = srb%96; int r = rb>>5; int b = rb&31;
  int t = threadIdx.x, w = t>>6, l = t&63, wr = w>>1, wc = w&1;
  const u16* Abase = WT + (size_t)(s*15 + layer*3 + r)*16384;
  const u16* Bbase = h + ((size_t)s*cB*cN + (size_t)b*cN + (size_t)nt*128)*cD;
  f32x4 acc[4][4];
  #pragma unroll
  for (int i=0;i<4;++i){ acc[i][0]=f32x4{0,0,0,0}; acc[i][1]=f32x4{0,0,0,0}; acc[i][2]=f32x4{0,0,0,0}; acc[i][3]=f32x4{0,0,0,0}; }
  for (int kt=0; kt<2; ++kt){
    __syncthreads();
    stage16k(Abase, 256, kt*128, smA, w, l);
    stage16k(Bbase, 256, kt*128, smB, w, l);
    __syncthreads();
    mfma_tile<4,4>(smA, smB, wr<<6, wc<<6, l, acc);
  }
  const float* bias = (s ? critic_b : actor_b) + (layer*3 + r)*cD;
  __syncthreads();                       // all waves done reading smA/smB
  char* OPh = wc ? smB : smA;
  #pragma unroll
  for (int mf=0; mf<4; ++mf)
    #pragma unroll
    for (int nf=0; nf<4; ++nf)
      #pragma unroll
      for (int j=0; j<4; ++j){
        int e  = (wr<<6) + (mf<<4) + ((l>>4)<<2) + j;
        int mh = (nf<<4) + (l&15);
        *(u16*)(OPh + e*128 + mh*2) = f2bf(acc[mf][nf][j] + bias[e]);
      }
  __syncthreads();
  char* outB = (char*)(hwT + (size_t)((s*3+r)*cB + b)*cD*cN);
  flush16k(smA, outB, 1024, nt*256 + 0,   t);
  flush16k(smB, outB, 1024, nt*256 + 128, t);
}

// ================= K2F layer 0: adj-direct pipeline (R10-verified main loop) =================
// epilogue: writes h1^T [d][n] (for restructured layer 1) + rowsum rs; no fused k1.
__global__ __launch_bounds__(256,2) void k2f_l0(const float* __restrict__ adj, u16* __restrict__ adjT,
                                                const u16* __restrict__ hwT_in, u16* __restrict__ h1T,
                                                float* __restrict__ rs, const float* __restrict__ all_mask){
  __shared__ __align__(16) char pool[73728];
  int blk = blockIdx.x;                          // 512 blocks
  int xcd = blk & 7; int slot = blk >> 3;
  int b = (slot>>4)*8 + xcd;
  int rest = slot & 15; int s = rest>>3; int mt = rest&7;
  int t = threadIdx.x, w = t>>6, l = t&63, wr = w>>1, wc = w&1;
  const u16* hwB = hwT_in + (size_t)(s*3*cB + b)*cD*cN;
  const size_t hwRs = (size_t)cB*cD*cN;
  f32x4 sum[2][4];
  #pragma unroll
  for (int i=0;i<2;++i)
    #pragma unroll
    for (int j=0;j<4;++j) sum[i][j]=f32x4{0,0,0,0};

  f32x4 a3[3][2][4];
  #pragma unroll
  for (int r=0;r<3;++r)
    #pragma unroll
    for (int i=0;i<2;++i)
      #pragma unroll
      for (int j=0;j<4;++j) a3[r][i][j]=f32x4{0,0,0,0};
  float rsr[3] = {0.f, 0.f, 0.f};
  const int nl  = t>>2;
  const int m8  = (t&3)*2;
  const float* asrc = adj + ((size_t)(b*cN + mt*64 + nl)*cN + m8*8)*3;
  float4 v[12];
  #pragma unroll
  for (int q=0;q<12;++q) v[q] = ((const float4*)asrc)[q];      // prologue: kt=0
  for (int kt=0; kt<8; ++kt){
    __builtin_amdgcn_s_barrier();
    __builtin_amdgcn_sched_barrier(0);
    stage16k(hwB,        1024, kt*128, pool+24576, w, l);
    stage16k(hwB+hwRs,   1024, kt*128, pool+40960, w, l);
    stage16k(hwB+2*hwRs, 1024, kt*128, pool+57344, w, l);
    __builtin_amdgcn_sched_barrier(0);
    const float* vf = (const float*)v;
    __align__(16) u16 o[2][3][8];
    #pragma unroll
    for (int i=0;i<2;++i)
      #pragma unroll
      for (int r=0;r<3;++r)
        #pragma unroll
        for (int k=0;k<8;++k){
          float raw = vf[i*24 + k*3 + r];
          o[i][r][k] = f2bf(raw);
          rsr[r] += raw;
        }
    #pragma unroll
    for (int i=0;i<2;++i){
      int m8i = m8 + i;
      #pragma unroll
      for (int r=0;r<3;++r)
        *(int4*)(pool + r*8192 + nl*128 + ((m8i*16) ^ ((nl&7)<<4))) = *(const int4*)&o[i][r][0];
    }
    if (kt < 7){
      const float* sp = asrc + (size_t)(kt+1)*64*3;
      #pragma unroll
      for (int q=0;q<12;++q) v[q] = ((const float4*)sp)[q];
    }
    __builtin_amdgcn_sched_barrier(0);
    if (kt < 7) asm volatile("s_waitcnt vmcnt(12)" ::: "memory");
    else        asm volatile("s_waitcnt vmcnt(0)"  ::: "memory");
    asm volatile("s_waitcnt lgkmcnt(0)" ::: "memory");
    __builtin_amdgcn_sched_barrier(0);
    __builtin_amdgcn_s_barrier();
    __builtin_amdgcn_sched_barrier(0);
    if (s == 0){
      #pragma unroll
      for (int r=0;r<3;++r){
        char* gb = (char*)adjT + (((size_t)(r*cB + b)*cN + (size_t)mt*64)*cN + (size_t)kt*64)*2;
        #pragma unroll
        for (int j=0;j<2;++j){
          int p = j*4096 + t*16;
          int n2 = p>>7, chunk = p&127;
          int4 val = *(const int4*)(pool + r*8192 + n2*128 + (chunk ^ ((n2&7)<<4)));
          *(int4*)(gb + (size_t)n2*1024 + chunk) = val;
        }
      }
    }
    #pragma unroll
    for (int r=0;r<3;++r)
      mfma_tile<2,4>(pool + r*8192, pool + 24576 + r*16384, wr<<5, wc<<6, l, a3[r]);
  }
  #pragma unroll
  for (int r=0;r<3;++r)
    #pragma unroll
    for (int mf=0;mf<2;++mf)
      #pragma unroll
      for (int nf=0;nf<4;++nf)
        #pragma unroll
        for (int j=0;j<4;++j)
          sum[mf][nf][j] += fmaxf(a3[r][mf][nf][j], 0.f);
  // rowsum reduce across the 4 lanes of each n-row; store (s==0 only)
  #pragma unroll
  for (int r=0;r<3;++r){
    rsr[r] += __shfl_xor(rsr[r], 1, 64);
    rsr[r] += __shfl_xor(rsr[r], 2, 64);
    if (s == 0 && (t&3) == 0) rs[((size_t)r*cB + b)*cN + mt*64 + nl] = rsr[r];
  }
  __syncthreads();
  char* hT0 = pool;
  char* hT1 = pool + 8192;
  #pragma unroll
  for (int mf=0; mf<2; ++mf)
    #pragma unroll
    for (int nf=0; nf<4; ++nf)
      #pragma unroll
      for (int j=0; j<4; ++j){
        int nloc = (wr<<5) + (mf<<4) + ((l>>4)<<2) + j;
        int e    = (wc<<6) + (nf<<4) + (l&15);
        int n    = mt*64 + nloc;
        u16 hv = f2bf(sum[mf][nf][j] * all_mask[b*cN + n]);
        char* base = (e & 64) ? hT1 : hT0;
        *(u16*)(base + nloc*128 + (((e&63)*2) ^ ((nloc&7)<<4))) = hv;
      }
  __syncthreads();
  // transposed flush: h1T[s][b][d][n] dense 128B rows
  char* gdst = (char*)(h1T + (size_t)(s*cB + b)*cD*cN);
  #pragma unroll
  for (int j=0;j<4;++j){
    int p = j*4096 + t*16;
    int d = p>>7; int nbyte = p&127; int nbase = nbyte>>1;
    char* panel = (d & 64) ? hT1 : hT0;
    int colb = (d & 63)*2;
    __align__(16) u16 o2[8];
    #pragma unroll
    for (int k=0;k<8;++k){
      int nloc = nbase + k;
      o2[k] = *(const u16*)(panel + nloc*128 + (colb ^ ((nloc&7)<<4)));
    }
    *(int4*)(gdst + (size_t)d*1024 + mt*128 + nbyte) = *(const int4*)o2;
  }
}

// ================= K2G layers 1..4 (restructured): h_next = mask*sum_r relu((adj_r@h)W_r + rs_r*b_r) =================
__global__ __launch_bounds__(256,2) void k2g(const u16* __restrict__ adjT,
                                             const u16* __restrict__ hT_in, u16* __restrict__ hT_out,
                                             const float* __restrict__ all_mask, const u16* __restrict__ WT,
                                             const float* __restrict__ actor_b, const float* __restrict__ critic_b,
                                             const float* __restrict__ rs, u16* __restrict__ hfin, int layer){
  __shared__ __align__(16) char pool[57344];
  // stage1: A@0 (8K), B@8192 (16K); P@24576 (2x8K); stage2: W0@0 (16K), W1@40960 (16K)
  int blk = blockIdx.x;                          // 512 blocks
  int xcd = blk & 7; int slot = blk >> 3;        // all (s,mt) of one b on one XCD
  int b = (slot>>4)*8 + xcd;
  int rest = slot & 15; int s = rest>>3; int mt = rest&7;
  int t = threadIdx.x, w = t>>6, l = t&63, wr = w>>1, wc = w&1;
  const u16* adjB = adjT + ((size_t)b*cN + (size_t)mt*64)*cN;
  const size_t adjRs_ = (size_t)cB*cN*cN;
  const u16* hTb = hT_in + (size_t)(s*cB + b)*cD*cN;      // [128 d][512 m]
  char* A  = pool;
  char* Bp = pool + 8192;
  char* P0 = pool + 24576;
  char* P1 = pool + 32768;
  char* W0 = pool;                 // overlaps A/B (stage1 finished when used)
  char* W1 = pool + 40960;
  f32x4 sum[2][4];
  #pragma unroll
  for (int i=0;i<2;++i)
    #pragma unroll
    for (int j=0;j<4;++j) sum[i][j]=f32x4{0,0,0,0};
  for (int r=0; r<3; ++r){
    // ---- stage 1: P = adj_r_tile @ h  (C[n][d], K=512 over m) ----
    f32x4 acc[2][4];
    #pragma unroll
    for (int i=0;i<2;++i)
      #pragma unroll
      for (int j=0;j<4;++j) acc[i][j]=f32x4{0,0,0,0};
    for (int kt=0; kt<8; ++kt){
      __syncthreads();                           // prev reads of A/B/W0 region done
      stage8k (adjB + (size_t)r*adjRs_, 1024, kt*128, A, w, l);
      stage16k(hTb,                     1024, kt*128, Bp, w, l);
      __syncthreads();
      mfma_tile<2,4>(A, Bp, wr<<5, wc<<6, l, acc);
    }
    // ---- P -> bf16 LDS panels [64 n][128 d split in two 64-d halves] ----
    #pragma unroll
    for (int mf=0; mf<2; ++mf)
      #pragma unroll
      for (int nf=0; nf<4; ++nf)
        #pragma unroll
        for (int j=0; j<4; ++j){
          int nloc = (wr<<5) + (mf<<4) + ((l>>4)<<2) + j;
          int d    = (wc<<6) + (nf<<4) + (l&15);
          char* panel = (d & 64) ? P1 : P0;
          *(u16*)(panel + nloc*128 + (((d&63)*2) ^ ((nloc&7)<<4))) = f2bf(acc[mf][nf][j]);
        }
    __syncthreads();                             // P visible; A/B reads done -> W can overwrite
    // ---- stage 2: msg = P @ W_r + rs_r*b_r ----
    const u16* Wbase = WT + (size_t)(s*15 + layer*3 + r)*16384;
    stage16k(Wbase, 256, 0,   W0, w, l);         // W^T rows e, d 0..63
    stage16k(Wbase, 256, 128, W1, w, l);         // W^T rows e, d 64..127
    __syncthreads();
    f32x4 acc2[2][4];
    #pragma unroll
    for (int i=0;i<2;++i)
      #pragma unroll
      for (int j=0;j<4;++j) acc2[i][j]=f32x4{0,0,0,0};
    mfma_tile<2,4>(P0, W0, wr<<5, wc<<6, l, acc2);
    mfma_tile<2,4>(P1, W1, wr<<5, wc<<6, l, acc2);
    const float* bias = (s ? critic_b : actor_b) + (layer*3 + r)*cD;
    const float* rsr  = rs + ((size_t)r*cB + b)*cN + (size_t)mt*64;
    #pragma unroll
    for (int mf=0; mf<2; ++mf)
      #pragma unroll
      for (int nf=0; nf<4; ++nf)
        #pragma unroll
        for (int j=0; j<4; ++j){
          int nloc = (wr<<5) + (mf<<4) + ((l>>4)<<2) + j;
          int e    = (wc<<6) + (nf<<4) + (l&15);
          sum[mf][nf][j] += fmaxf(acc2[mf][nf][j] + rsr[nloc]*bias[e], 0.f);
        }
  }
  __syncthreads();                               // stage2 reads done; reuse P panels for h
  // ---- mask; write h into P panels [n][d] ----
  #pragma unroll
  for (int mf=0; mf<2; ++mf)
    #pragma unroll
    for (int nf=0; nf<4; ++nf)
      #pragma unroll
      for (int j=0; j<4; ++j){
        int nloc = (wr<<5) + (mf<<4) + ((l>>4)<<2) + j;
        int e    = (wc<<6) + (nf<<4) + (l&15);
        int n    = mt*64 + nloc;
        u16 hv = f2bf(sum[mf][nf][j] * all_mask[b*cN + n]);
        char* panel = (e & 64) ? P1 : P0;
        *(u16*)(panel + nloc*128 + (((e&63)*2) ^ ((nloc&7)<<4))) = hv;
      }
  __syncthreads();
  if (layer == cL-1){
    // final: write [n][d] rows for head consumers
    char* gdst = (char*)(hfin + ((size_t)(s*cB + b)*cN + (size_t)mt*64)*cD);
    #pragma unroll
    for (int j=0;j<4;++j){
      int p = j*4096 + t*16;
      int nloc = p>>8, ebyte = p&255;
      char* panel = (ebyte & 128) ? P1 : P0;
      int chunk = ebyte & 127;
      int4 v2 = *(const int4*)(panel + nloc*128 + (chunk ^ ((nloc&7)<<4)));
      *(int4*)(gdst + (size_t)nloc*256 + ebyte) = v2;
    }
  } else {
    // transposed flush: hT_out[s][b][d][n] dense 128B rows
    char* gdst = (char*)(hT_out + (size_t)(s*cB + b)*cD*cN);
    #pragma unroll
    for (int j=0;j<4;++j){
      int p = j*4096 + t*16;
      int d = p>>7; int nbyte = p&127; int nbase = nbyte>>1;
      char* panel = (d & 64) ? P1 : P0;
      int colb = (d & 63)*2;
      __align__(16) u16 o2[8];
      #pragma unroll
      for (int k=0;k<8;++k){
        int nloc = nbase + k;
        o2[k] = *(const u16*)(panel + nloc*128 + (colb ^ ((nloc&7)<<4)));
      }
      *(int4*)(gdst + (size_t)d*1024 + mt*128 + nbyte) = *(const int4*)o2;
    }
  }
}

// ================= pooling stage 1: partial sum/max over 32-row chunks =================
__global__ __launch_bounds__(256) void pool_part(const u16* __restrict__ xc, const float* __restrict__ cmask,
                                                 float* __restrict__ part){
  int blk = blockIdx.x;               // b*16 + c
  int b = blk >> 4, c = blk & 15;
  int t = threadIdx.x; int d = t & 127, nh = t >> 7;
  const u16* x = xc + ((size_t)b*cN + c*32 + nh*16)*cD;
  const float* cm = cmask + (size_t)b*cN + c*32 + nh*16;
  float sm = 0.f, mx = -3e38f;
  #pragma unroll
  for (int i=0;i<16;++i){
    float v = bf2f(x[(size_t)i*cD + d]);
    float m = cm[i];
    sm += v*m;
    mx = fmaxf(mx, v + (m==1.0f ? 0.f : NEGV));
  }
  __shared__ float s_sm[2][128], s_mx[2][128];
  s_sm[nh][d] = sm; s_mx[nh][d] = mx;
  __syncthreads();
  if (nh == 0){
    float* dst = part + ((size_t)b*16 + c)*256;
    dst[d]       = sm + s_sm[1][d];
    dst[128 + d] = fmaxf(mx, s_mx[1][d]);
  }
}

// ================= actor: end logits as MFMA GEMM (computes sc internally) =================
__global__ __launch_bounds__(256,2) void end_logits2(const u16* __restrict__ xa, const u16* __restrict__ WT,
                                                     const u16* __restrict__ Wc, const int* __restrict__ focus,
                                                     const float* __restrict__ be1,
                                                     const float* __restrict__ prob_mask, float* __restrict__ logits){
  __shared__ __align__(16) char smA[16384];
  __shared__ __align__(16) char smB[16384];
  __shared__ float s_start[128], sh_sc[128], sh_w2[128], rowsum[2][128];
  int blk = blockIdx.x;                // b*4 + nt
  int nt = blk & 3, b = blk >> 2;
  int t = threadIdx.x, w = t>>6, l = t&63, wr = w>>1, wc = w&1;
  if (t < 128){
    s_start[t] = bf2f(xa[((size_t)b*cN + focus[b])*cD + t]);
    sh_w2[t]   = bf2f(Wc[WOF_WE2 + t]);
  }
  __syncthreads();
  if (t < 128){
    float a = be1[t];
    #pragma unroll 4
    for (int k=0;k<128;++k) a += s_start[k]*bf2f(Wc[WOF_WE1 + k*cD + t]);
    sh_sc[t] = a;
  }
  const u16* Abase = xa + ((size_t)b*cN + (size_t)nt*128)*cD;
  const u16* Bbase = WT + (size_t)30*16384;
  f32x4 acc[4][4];
  #pragma unroll
  for (int i=0;i<4;++i){ acc[i][0]=f32x4{0,0,0,0}; acc[i][1]=f32x4{0,0,0,0}; acc[i][2]=f32x4{0,0,0,0}; acc[i][3]=f32x4{0,0,0,0}; }
  for (int kt=0; kt<2; ++kt){
    __syncthreads();
    stage16k(Abase, 256, kt*128, smA, w, l);
    stage16k(Bbase, 256, kt*128, smB, w, l);
    __syncthreads();
    mfma_tile<4,4>(smA, smB, wr<<6, wc<<6, l, acc);
  }
  float p[4][4];
  #pragma unroll
  for (int mf=0;mf<4;++mf)
    #pragma unroll
    for (int j=0;j<4;++j) p[mf][j] = 0.f;
  #pragma unroll
  for (int mf=0; mf<4; ++mf)
    #pragma unroll
    for (int nf=0; nf<4; ++nf){
      int e = (wc<<6) + (nf<<4) + (l&15);
      float scv = sh_sc[e], w2 = sh_w2[e];
      #pragma unroll
      for (int j=0; j<4; ++j)
        p[mf][j] += fmaxf(acc[mf][nf][j] + scv, 0.f) * w2;
    }
  #pragma unroll
  for (int mf=0; mf<4; ++mf)
    #pragma unroll
    for (int j=0; j<4; ++j){
      float v = p[mf][j];
      #pragma unroll
      for (int o=1;o<16;o<<=1) v += __shfl_xor(v, o, 64);
      if ((l&15)==0) rowsum[wc][(wr<<6) + (mf<<4) + ((l>>4)<<2) + j] = v;
    }
  __syncthreads();
  if (t < 128){
    int n = nt*128 + t;
    float pm = (prob_mask[b*cN + n]==1.0f) ? 0.f : NEGV;
    logits[b*cN + n] = rowsum[0][t] + rowsum[1][t] + pm;
  }
}

// ================= fused final heads: qvalue + end softmax/entropy + bond/stop =================
__global__ __launch_bounds__(128) void heads_final(const float* __restrict__ part, const u16* __restrict__ Wc,
                                                   const float* __restrict__ bq1, const float* __restrict__ bq2,
                                                   const float* __restrict__ logits, const int* __restrict__ action,
                                                   const u16* __restrict__ xa, const int* __restrict__ focus,
                                                   const float* __restrict__ bb1, const float* __restrict__ bs1,
                                                   float* __restrict__ out){
  int b = blockIdx.x, t = threadIdx.x;
  __shared__ float qin[256];
  __shared__ float sv[128], ev[128];
  __shared__ float redq[2], red5[5][2];
  __shared__ float HendSh;
  sv[t] = bf2f(xa[((size_t)b*cN + focus[b])*cD + t]);
  ev[t] = bf2f(xa[((size_t)b*cN + action[b*3])*cD + t]);
  float sm = 0.f, mx = -3e38f;
  #pragma unroll
  for (int c=0;c<16;++c){
    const float* src = part + ((size_t)b*16 + c)*256;
    sm += src[t];
    mx = fmaxf(mx, src[128 + t]);
  }
  qin[t] = sm; qin[128+t] = mx;
  __syncthreads();
  float acc = bq1[t];
  #pragma unroll 4
  for (int k=0; k<256; ++k) acc += qin[k]*bf2f(Wc[WOF_WQ1 + k*cD + t]);
  float hc = fmaxf(acc,0.f)*bf2f(Wc[WOF_WQ2 + t]);
  #pragma unroll
  for (int o=32;o>0;o>>=1) hc += __shfl_down(hc, o, 64);
  if ((t&63)==0) redq[t>>6] = hc;
  if (t < 64){
    float v[8];
    #pragma unroll
    for (int i=0;i<8;++i) v[i] = logits[b*cN + i*64 + t];
    float m = v[0];
    #pragma unroll
    for (int i=1;i<8;++i) m = fmaxf(m, v[i]);
    #pragma unroll
    for (int o=32;o>0;o>>=1) m = fmaxf(m, __shfl_xor(m, o, 64));
    float e[8]; float s = 0.f;
    #pragma unroll
    for (int i=0;i<8;++i){ e[i] = expf(v[i]-m); s += e[i]; }
    #pragma unroll
    for (int o=32;o>0;o>>=1) s += __shfl_xor(s, o, 64);
    float lns = logf(s);
    float pl = 0.f;
    #pragma unroll
    for (int i=0;i<8;++i){ float p = e[i]/s; pl += p*((v[i]-m) - lns); }
    #pragma unroll
    for (int o=32;o>0;o>>=1) pl += __shfl_xor(pl, o, 64);
    int idx = action[b*3 + 0];
    if (t == (idx & 63)){
      float pe = 0.f;
      #pragma unroll
      for (int i=0;i<8;++i) if ((idx>>6)==i) pe = e[i];
      out[b*3 + 0] = pe / s;
    }
    if (t == 0) HendSh = -pl;
  }
  __syncthreads();
  float ab = bb1[t], as_ = bs1[t];
  #pragma unroll 4
  for (int k=0;k<128;++k){ float svk = sv[k]; ab += svk*bf2f(Wc[WOF_WB1 + k*cD + t]); as_ += svk*bf2f(Wc[WOF_WS1 + k*cD + t]); }
  #pragma unroll 4
  for (int k=0;k<128;++k) ab += ev[k]*bf2f(Wc[WOF_WB1 + (128+k)*cD + t]);
  float hb = fmaxf(ab,0.f), hs = fmaxf(as_,0.f);
  float r0 = hb*bf2f(Wc[WOF_WB2 + t*3+0]);
  float r1 = hb*bf2f(Wc[WOF_WB2 + t*3+1]);
  float r2 = hb*bf2f(Wc[WOF_WB2 + t*3+2]);
  float r3 = hs*bf2f(Wc[WOF_WS2 + t*2+0]);
  float r4 = hs*bf2f(Wc[WOF_WS2 + t*2+1]);
  #pragma unroll
  for (int o=32;o>0;o>>=1){
    r0 += __shfl_xor(r0,o,64); r1 += __shfl_xor(r1,o,64); r2 += __shfl_xor(r2,o,64);
    r3 += __shfl_xor(r3,o,64); r4 += __shfl_xor(r4,o,64);
  }
  if ((t&63)==0){ int wid=t>>6; red5[0][wid]=r0; red5[1][wid]=r1; red5[2][wid]=r2; red5[3][wid]=r3; red5[4][wid]=r4; }
  __syncthreads();
  if (t==0){
    out[128 + b] = redq[0] + redq[1] + bq2[0];
    auto xlx = [](float p){ return p > 0.f ? p*logf(p) : 0.f; };
    float bl0=red5[0][0]+red5[0][1], bl1=red5[1][0]+red5[1][1], bl2=red5[2][0]+red5[2][1];
    float sl0=red5[3][0]+red5[3][1], sl1=red5[4][0]+red5[4][1];
    float m = fmaxf(fmaxf(bl0,bl1),bl2);
    float e0=expf(bl0-m), e1=expf(bl1-m), e2=expf(bl2-m); float S=e0+e1+e2;
    float p0=e0/S, p1=e1/S, p2=e2/S;
    float Hb = -(xlx(p0) + xlx(p1) + xlx(p2));
    int a1 = action[b*3+1];
    out[b*3+1] = (a1==0)?p0:((a1==1)?p1:p2);
    float ms = fmaxf(sl0,sl1);
    float f0=expf(sl0-ms), f1=expf(sl1-ms); float T=f0+f1;
    float q0=f0/T, q1=f1/T;
    float Hs = -(xlx(q0) + xlx(q1));
    int a2 = action[b*3+2];
    out[b*3+2] = (a2==0)?q0:q1;
    out[96+b] = HendSh + Hb + Hs;
  }
}

// ================= launcher =================
extern "C" void kernel_launch(void* const* d_in, const int* in_sizes, int n_in,
                              void* d_out, int out_size, void* d_ws, size_t ws_size,
                              hipStream_t stream){
  const float* fatoms      = (const float*)d_in[0];
  const float* adj         = (const float*)d_in[1];
  const float* all_mask    = (const float*)d_in[2];
  const float* current_mask= (const float*)d_in[3];
  const float* prob_mask   = (const float*)d_in[4];
  const int*   focus       = (const int*)d_in[5];
  const int*   action      = (const int*)d_in[6];
  const float* actor_b     = (const float*)d_in[10];
  const float* critic_b    = (const float*)d_in[12];
  const float* be1         = (const float*)d_in[14];
  const float* bb1         = (const float*)d_in[17];
  const float* bs1         = (const float*)d_in[20];
  const float* bq1         = (const float*)d_in[23];
  const float* bq2         = (const float*)d_in[25];

  char* ws = (char*)d_ws;
  size_t o = 0;
  u16* adjT = (u16*)(ws + o);  o += (size_t)3*cB*cN*cN*2;        // 50.3 MB (written by k2f_l0)
  u16* WT   = (u16*)(ws + o);  o += (size_t)31*16384*2;          //  1.0 MB
  u16* hbuf = (u16*)(ws + o);  o += (size_t)2*2*cB*cN*cD*2;      // 16.8 MB (phase0=h0, phase1=hfin)
  u16* hwT0 = (u16*)(ws + o);  o += (size_t)2*3*cB*cD*cN*2;      // 25.2 MB (layer 0 only)
  u16* hTa  = (u16*)(ws + o);  o += (size_t)2*cB*cD*cN*2;        //  8.4 MB (h^T ping)
  u16* hTb  = (u16*)(ws + o);  o += (size_t)2*cB*cD*cN*2;        //  8.4 MB (h^T pong)
  u16* Wcan = (u16*)(ws + o);  o += (size_t)WTOTAL*2;
  float* rs     = (float*)(ws + o); o += (size_t)3*cB*cN*4;      //  0.2 MB
  float* part   = (float*)(ws + o); o += (size_t)cB*16*256*4;
  float* logits = (float*)(ws + o); o += (size_t)cB*cN*4;
  float* out = (float*)d_out;

  WPtrs wp;
  wp.p[0]=d_in[7];  wp.p[1]=d_in[8];  wp.p[2]=d_in[9];  wp.p[3]=d_in[11];
  wp.p[4]=d_in[13]; wp.p[5]=d_in[15]; wp.p[6]=d_in[16]; wp.p[7]=d_in[18];
  wp.p[8]=d_in[19]; wp.p[9]=d_in[21]; wp.p[10]=d_in[22]; wp.p[11]=d_in[24];

  canon_w<<<dim3((WTOTAL+255)/256), dim3(256), 0, stream>>>(wp, Wcan);
  prep_w<<<dim3(31), dim3(256), 0, stream>>>(Wcan, WT);
  emb<<<dim3(2*cB*cN), dim3(128), 0, stream>>>(fatoms, Wcan, hbuf);

  const size_t hstride = (size_t)2*cB*cN*cD;
  u16* hfin = hbuf + hstride;
  k1_hw<<<dim3(768), dim3(256), 0, stream>>>(WT, hbuf, actor_b, critic_b, hwT0, 0);
  k2f_l0<<<dim3(512), dim3(256), 0, stream>>>(adj, adjT, hwT0, hTa, rs, all_mask);
  for (int l=1; l<cL; ++l){
    u16* tin  = (l&1) ? hTa : hTb;
    u16* tout = (l&1) ? hTb : hTa;
    k2g<<<dim3(512), dim3(256), 0, stream>>>(adjT, tin, tout, all_mask, WT, actor_b, critic_b, rs, hfin, l);
  }
  const u16* xa = hfin;
  const u16* xc = hfin + (size_t)cB*cN*cD;

  end_logits2<<<dim3(cB*4), dim3(256), 0, stream>>>(xa, WT, Wcan, focus, be1, prob_mask, logits);
  pool_part<<<dim3(cB*16), dim3(256), 0, stream>>>(xc, current_mask, part);
  heads_final<<<dim3(cB), dim3(128), 0, stream>>>(part, Wcan, bq1, bq2, logits, action, xa, focus, bb1, bs1, out);
}

// Round 13
// 251.040 us; speedup vs baseline: 1.0484x; 1.0202x over previous
//
#include <hip/hip_runtime.h>
#include <cstdint>
#include <cstddef>

typedef unsigned short u16;
typedef __bf16 bfx8 __attribute__((ext_vector_type(8)));
typedef float f32x4 __attribute__((ext_vector_type(4)));

#define NEGV -10000000.0f
constexpr int cB = 32, cN = 512, cD = 128, cF = 20, cL = 5;

__device__ __forceinline__ float bf2f(u16 h){ unsigned u = ((unsigned)h)<<16; return __builtin_bit_cast(float,u); }
__device__ __forceinline__ u16 f2bf(float f){ unsigned u = __builtin_bit_cast(unsigned,f); return (u16)((u + 0x7fffu + ((u>>16)&1u))>>16); }

// ===== canonical weight buffer layout (element offsets, bf16) =====
constexpr int WOF_EMB  = 0;
constexpr int WOF_CEMB = 2560;
constexpr int WOF_AW   = 5120;
constexpr int WOF_CW   = 250880;
constexpr int WOF_WE1  = 496640;
constexpr int WOF_WE2  = 529408;
constexpr int WOF_WB1  = 529536;
constexpr int WOF_WB2  = 562304;
constexpr int WOF_WS1  = 562688;
constexpr int WOF_WS2  = 579072;
constexpr int WOF_WQ1  = 579328;
constexpr int WOF_WQ2  = 612096;
constexpr int WTOTAL   = 612224;

struct WPtrs { const void* p[12]; };

// ================= canonicalize weights to bf16 (self-detecting dtype) =================
__global__ __launch_bounds__(256) void canon_w(WPtrs wp, u16* __restrict__ Wc){
  __shared__ int s_flag;
  int t = threadIdx.x;
  if (t == 0) s_flag = 0;
  __syncthreads();
  const u16* probe = (const u16*)wp.p[2];
  int big = 0;
  #pragma unroll
  for (int i=0;i<2;++i){
    float a = fabsf(bf2f(probe[i*256 + t]));
    if (!(a < 1e10f)) big = 1;
  }
  if (__any(big)) s_flag = 1;       // benign race: only ever sets 1
  __syncthreads();
  int flag = s_flag;
  int i = blockIdx.x*256 + t;
  if (i >= WTOTAL) return;
  constexpr int offs[13] = {WOF_EMB, WOF_CEMB, WOF_AW, WOF_CW, WOF_WE1, WOF_WE2,
                            WOF_WB1, WOF_WB2, WOF_WS1, WOF_WS2, WOF_WQ1, WOF_WQ2, WTOTAL};
  int a = 0;
  #pragma unroll
  for (int k = 1; k < 12; ++k) if (i >= offs[k]) a = k;
  int off = i - offs[a];
  const void* p = wp.p[a];
  Wc[i] = flag ? f2bf(((const float*)p)[off]) : ((const u16*)p)[off];
}

// ================= prep: transpose weights; blk 0..29 GCN W, blk 30 = We1 bottom =================
__global__ __launch_bounds__(256) void prep_w(const u16* __restrict__ Wc, u16* __restrict__ WT){
  __shared__ u16 sh[128*129];
  int blk = blockIdx.x;
  const u16* in;
  if (blk < 30){
    int s = blk/15; int lr = blk%15;
    in = Wc + (s ? WOF_CW : WOF_AW) + (size_t)lr*16384;
  } else {
    in = Wc + WOF_WE1 + 128*cD;           // We1 bottom half [k=128..255][e]
  }
  u16* out = WT + (size_t)blk*16384;
  int t = threadIdx.x;
  #pragma unroll 4
  for (int i=0;i<64;++i){ int idx=i*256+t; int d=idx>>7, e=idx&127; sh[e*129+d]=in[idx]; }
  __syncthreads();
  #pragma unroll 4
  for (int i=0;i<64;++i){ int idx=i*256+t; int e=idx>>7, d=idx&127; out[idx]=sh[e*129+d]; }
}

// ================= emb: h0 = relu(fatoms @ W) bf16, both stacks =================
__global__ __launch_bounds__(128) void emb(const float* __restrict__ fatoms, const u16* __restrict__ Wc, u16* __restrict__ h0){
  int row = blockIdx.x;
  int s = row >> 14; int bn = row & 16383;
  __shared__ float fa[cF];
  int t = threadIdx.x;
  if (t < cF) fa[t] = fatoms[(size_t)bn*cF + t];
  __syncthreads();
  const u16* W = Wc + (s ? WOF_CEMB : WOF_EMB);
  float acc = 0.f;
  #pragma unroll
  for (int f=0; f<cF; ++f) acc += fa[f]*bf2f(W[f*cD + t]);
  h0[((size_t)s*cB*cN + bn)*cD + t] = f2bf(fmaxf(acc,0.f));
}

// ================= MFMA tile helpers (m97 recipe) =================
__device__ __forceinline__ void stage16k(const u16* gbase, int ldaB, int ktB, char* sm, int w, int l){
  #pragma unroll
  for (int i=0;i<4;++i){
    int c = (w<<2) + i;
    int row = (c<<3) + (l>>3);
    const char* src = (const char*)gbase + (size_t)row*ldaB + ktB + (((l&7)^(row&7))<<4);
    __builtin_amdgcn_global_load_lds((const __attribute__((address_space(1))) void*)src,
                                     (__attribute__((address_space(3))) void*)(sm + (c<<10)), 16, 0, 0);
  }
}
__device__ __forceinline__ void stage8k(const u16* gbase, int ldaB, int ktB, char* sm, int w, int l){
  #pragma unroll
  for (int i=0;i<2;++i){
    int c = (w<<1) + i;
    int row = (c<<3) + (l>>3);
    const char* src = (const char*)gbase + (size_t)row*ldaB + ktB + (((l&7)^(row&7))<<4);
    __builtin_amdgcn_global_load_lds((const __attribute__((address_space(1))) void*)src,
                                     (__attribute__((address_space(3))) void*)(sm + (c<<10)), 16, 0, 0);
  }
}
__device__ __forceinline__ bfx8 readfrag(const char* sm, int row, int kk, int l){
  int col = ((kk<<6) + ((l>>4)<<4)) ^ ((row&7)<<4);
  return *(const bfx8*)(sm + row*128 + col);
}
template<int MF,int NF>
__device__ __forceinline__ void mfma_tile(const char* A, const char* Bm, int ra, int rb, int l, f32x4 (&acc)[MF][NF]){
  #pragma unroll
  for (int kk=0; kk<2; ++kk){
    bfx8 af[MF], bv[NF];
    #pragma unroll
    for (int f=0; f<MF; ++f) af[f] = readfrag(A,  ra+(f<<4)+(l&15), kk, l);
    #pragma unroll
    for (int f=0; f<NF; ++f) bv[f] = readfrag(Bm, rb+(f<<4)+(l&15), kk, l);
    #pragma unroll
    for (int mf=0; mf<MF; ++mf)
      #pragma unroll
      for (int nf=0; nf<NF; ++nf)
        acc[mf][nf] = __builtin_amdgcn_mfma_f32_16x16x32_bf16(af[mf], bv[nf], acc[mf][nf], 0,0,0);
  }
}
// coalesced panel flush: 16KB LDS panel [128 rows][128B] -> global rows of ld=ldB at
// byte col base colB. Per instruction j, lanes cover contiguous 4KB (dense 128B rows).
__device__ __forceinline__ void flush16k(const char* P, char* gbase, int ldB, int colB, int t){
  #pragma unroll
  for (int j=0;j<4;++j){
    int p = j*4096 + t*16;
    int e = p>>7, col = p&127;
    int4 v = *(const int4*)(P + p);
    *(int4*)(gbase + (size_t)e*ldB + colB + col) = v;
  }
}

// ================= K1 (layer 0 only): hw^T = W^T h + b =================
__global__ __launch_bounds__(256,2) void k1_hw(const u16* __restrict__ WT, const u16* __restrict__ h,
                                               const float* __restrict__ actor_b, const float* __restrict__ critic_b,
                                               u16* __restrict__ hwT, int layer){
  __shared__ __align__(16) char smA[16384];
  __shared__ __align__(16) char smB[16384];
  int blk = blockIdx.x;
  int nt = blk & 3; int srb = blk >> 2;
  int s = srb/96; int rb = srb%96; int r = rb>>5; int b = rb&31;
  int t = threadIdx.x, w = t>>6, l = t&63, wr = w>>1, wc = w&1;
  const u16* Abase = WT + (size_t)(s*15 + layer*3 + r)*16384;
  const u16* Bbase = h + ((size_t)s*cB*cN + (size_t)b*cN + (size_t)nt*128)*cD;
  f32x4 acc[4][4];
  #pragma unroll
  for (int i=0;i<4;++i){ acc[i][0]=f32x4{0,0,0,0}; acc[i][1]=f32x4{0,0,0,0}; acc[i][2]=f32x4{0,0,0,0}; acc[i][3]=f32x4{0,0,0,0}; }
  for (int kt=0; kt<2; ++kt){
    __syncthreads();
    stage16k(Abase, 256, kt*128, smA, w, l);
    stage16k(Bbase, 256, kt*128, smB, w, l);
    __syncthreads();
    mfma_tile<4,4>(smA, smB, wr<<6, wc<<6, l, acc);
  }
  const float* bias = (s ? critic_b : actor_b) + (layer*3 + r)*cD;
  __syncthreads();                       // all waves done reading smA/smB
  char* OPh = wc ? smB : smA;
  #pragma unroll
  for (int mf=0; mf<4; ++mf)
    #pragma unroll
    for (int nf=0; nf<4; ++nf)
      #pragma unroll
      for (int j=0; j<4; ++j){
        int e  = (wr<<6) + (mf<<4) + ((l>>4)<<2) + j;
        int mh = (nf<<4) + (l&15);
        *(u16*)(OPh + e*128 + mh*2) = f2bf(acc[mf][nf][j] + bias[e]);
      }
  __syncthreads();
  char* outB = (char*)(hwT + (size_t)((s*3+r)*cB + b)*cD*cN);
  flush16k(smA, outB, 1024, nt*256 + 0,   t);
  flush16k(smB, outB, 1024, nt*256 + 128, t);
}

// ================= K2F layer 0: 64x128 tiles, 512 blocks, adj-direct pipeline =================
__global__ __launch_bounds__(256,2) void k2f_l0(const float* __restrict__ adj, u16* __restrict__ adjT,
                                                const u16* __restrict__ hwT_in, u16* __restrict__ hwT_out,
                                                const float* __restrict__ all_mask, const u16* __restrict__ WT,
                                                const float* __restrict__ actor_b, const float* __restrict__ critic_b){
  __shared__ __align__(16) char pool[73728];
  int blk = blockIdx.x;                          // 512 blocks
  int xcd = blk & 7; int slot = blk >> 3;
  int b = (slot>>4)*8 + xcd;
  int rest = slot & 15; int s = rest>>3; int mt = rest&7;
  int t = threadIdx.x, w = t>>6, l = t&63, wr = w>>1, wc = w&1;
  const u16* hwB = hwT_in + (size_t)(s*3*cB + b)*cD*cN;
  const size_t hwRs = (size_t)cB*cD*cN;
  f32x4 sum[2][4];
  #pragma unroll
  for (int i=0;i<2;++i)
    #pragma unroll
    for (int j=0;j<4;++j) sum[i][j]=f32x4{0,0,0,0};

  f32x4 a3[3][2][4];
  #pragma unroll
  for (int r=0;r<3;++r)
    #pragma unroll
    for (int i=0;i<2;++i)
      #pragma unroll
      for (int j=0;j<4;++j) a3[r][i][j]=f32x4{0,0,0,0};
  const int nl  = t>>2;
  const int m8  = (t&3)*2;
  const float* asrc = adj + ((size_t)(b*cN + mt*64 + nl)*cN + m8*8)*3;
  float4 v[12];
  #pragma unroll
  for (int q=0;q<12;++q) v[q] = ((const float4*)asrc)[q];      // prologue: kt=0
  for (int kt=0; kt<8; ++kt){
    __builtin_amdgcn_s_barrier();
    __builtin_amdgcn_sched_barrier(0);
    stage16k(hwB,        1024, kt*128, pool+24576, w, l);
    stage16k(hwB+hwRs,   1024, kt*128, pool+40960, w, l);
    stage16k(hwB+2*hwRs, 1024, kt*128, pool+57344, w, l);
    __builtin_amdgcn_sched_barrier(0);
    const float* vf = (const float*)v;
    __align__(16) u16 o[2][3][8];
    #pragma unroll
    for (int i=0;i<2;++i)
      #pragma unroll
      for (int r=0;r<3;++r)
        #pragma unroll
        for (int k=0;k<8;++k) o[i][r][k] = f2bf(vf[i*24 + k*3 + r]);
    #pragma unroll
    for (int i=0;i<2;++i){
      int m8i = m8 + i;
      #pragma unroll
      for (int r=0;r<3;++r)
        *(int4*)(pool + r*8192 + nl*128 + ((m8i*16) ^ ((nl&7)<<4))) = *(const int4*)&o[i][r][0];
    }
    if (kt < 7){
      const float* sp = asrc + (size_t)(kt+1)*64*3;
      #pragma unroll
      for (int q=0;q<12;++q) v[q] = ((const float4*)sp)[q];
    }
    __builtin_amdgcn_sched_barrier(0);
    if (kt < 7) asm volatile("s_waitcnt vmcnt(12)" ::: "memory");
    else        asm volatile("s_waitcnt vmcnt(0)"  ::: "memory");
    asm volatile("s_waitcnt lgkmcnt(0)" ::: "memory");
    __builtin_amdgcn_sched_barrier(0);
    __builtin_amdgcn_s_barrier();
    __builtin_amdgcn_sched_barrier(0);
    if (s == 0){
      #pragma unroll
      for (int r=0;r<3;++r){
        char* gb = (char*)adjT + (((size_t)(r*cB + b)*cN + (size_t)mt*64)*cN + (size_t)kt*64)*2;
        #pragma unroll
        for (int j=0;j<2;++j){
          int p = j*4096 + t*16;
          int n2 = p>>7, chunk = p&127;
          int4 val = *(const int4*)(pool + r*8192 + n2*128 + (chunk ^ ((n2&7)<<4)));
          *(int4*)(gb + (size_t)n2*1024 + chunk) = val;
        }
      }
    }
    #pragma unroll
    for (int r=0;r<3;++r)
      mfma_tile<2,4>(pool + r*8192, pool + 24576 + r*16384, wr<<5, wc<<6, l, a3[r]);
  }
  #pragma unroll
  for (int r=0;r<3;++r)
    #pragma unroll
    for (int mf=0;mf<2;++mf)
      #pragma unroll
      for (int nf=0;nf<4;++nf)
        #pragma unroll
        for (int j=0;j<4;++j)
          sum[mf][nf][j] += fmaxf(a3[r][mf][nf][j], 0.f);
  __syncthreads();
  char* hT0 = pool;
  char* hT1 = pool + 8192;
  char* OP  = pool + 57344;
  #pragma unroll
  for (int mf=0; mf<2; ++mf)
    #pragma unroll
    for (int nf=0; nf<4; ++nf)
      #pragma unroll
      for (int j=0; j<4; ++j){
        int nloc = (wr<<5) + (mf<<4) + ((l>>4)<<2) + j;
        int e    = (wc<<6) + (nf<<4) + (l&15);
        int n    = mt*64 + nloc;
        u16 hv = f2bf(sum[mf][nf][j] * all_mask[b*cN + n]);
        char* base = (e & 64) ? hT1 : hT0;
        *(u16*)(base + nloc*128 + (((e&63)*2) ^ ((nloc&7)<<4))) = hv;
      }
  char* W0 = pool + 24576;
  char* W1 = W0 + 16384;
  for (int r=0; r<3; ++r){
    __syncthreads();
    const u16* Wbase = WT + (size_t)(s*15 + 1*3 + r)*16384;       // layer+1 = 1
    stage16k(Wbase, 256, 0,   W0, w, l);
    stage16k(Wbase, 256, 128, W1, w, l);
    __syncthreads();
    f32x4 acc2[4][2];
    #pragma unroll
    for (int i=0;i<4;++i){ acc2[i][0]=f32x4{0,0,0,0}; acc2[i][1]=f32x4{0,0,0,0}; }
    mfma_tile<4,2>(W0, hT0, wr<<6, wc<<5, l, acc2);
    mfma_tile<4,2>(W1, hT1, wr<<6, wc<<5, l, acc2);
    const float* bias = (s ? critic_b : actor_b) + (1*3 + r)*cD;
    #pragma unroll
    for (int mf=0; mf<4; ++mf)
      #pragma unroll
      for (int nf=0; nf<2; ++nf)
        #pragma unroll
        for (int j=0; j<4; ++j){
          int e   = (wr<<6) + (mf<<4) + ((l>>4)<<2) + j;
          int m64 = (wc<<5) + (nf<<4) + (l&15);
          *(u16*)(OP + e*128 + m64*2) = f2bf(acc2[mf][nf][j] + bias[e]);
        }
    __syncthreads();
    char* outB = (char*)(hwT_out + (size_t)((s*3+r)*cB + b)*cD*cN);
    flush16k(OP, outB, 1024, mt*128, t);
  }
}

// ================= K2F layers 1..4: 64x128 tiles, 512 blocks = 2/CU =================
__global__ __launch_bounds__(256,2) void k2f_ln(const u16* __restrict__ adjT,
                                                const u16* __restrict__ hwT_in, u16* __restrict__ hwT_out,
                                                const float* __restrict__ all_mask, const u16* __restrict__ WT,
                                                const float* __restrict__ actor_b, const float* __restrict__ critic_b,
                                                u16* __restrict__ hfin, int layer){
  __shared__ __align__(16) char pool[73728];
  int blk = blockIdx.x;                          // 512 blocks
  int xcd = blk & 7; int slot = blk >> 3;
  int b = (slot>>4)*8 + xcd;
  int rest = slot & 15; int s = rest>>3; int mt = rest&7;
  int t = threadIdx.x, w = t>>6, l = t&63, wr = w>>1, wc = w&1;
  const u16* hwB = hwT_in + (size_t)(s*3*cB + b)*cD*cN;
  const size_t hwRs = (size_t)cB*cD*cN;
  f32x4 sum[2][4];
  #pragma unroll
  for (int i=0;i<2;++i)
    #pragma unroll
    for (int j=0;j<4;++j) sum[i][j]=f32x4{0,0,0,0};
  // LDS: smA at 0 (8K), smB at 8192 (16K)
  const u16* adjB = adjT + ((size_t)b*cN + (size_t)mt*64)*cN;
  const size_t adjRs = (size_t)cB*cN*cN;
  for (int r=0;r<3;++r){
    f32x4 acc[2][4];
    #pragma unroll
    for (int i=0;i<2;++i)
      #pragma unroll
      for (int j=0;j<4;++j) acc[i][j]=f32x4{0,0,0,0};
    for (int kt=0;kt<8;++kt){
      __syncthreads();
      stage8k (adjB + (size_t)r*adjRs, 1024, kt*128, pool, w, l);
      stage16k(hwB  + (size_t)r*hwRs,  1024, kt*128, pool+8192, w, l);
      __syncthreads();
      mfma_tile<2,4>(pool, pool+8192, wr<<5, wc<<6, l, acc);
    }
    #pragma unroll
    for (int mf=0;mf<2;++mf)
      #pragma unroll
      for (int nf=0;nf<4;++nf)
        #pragma unroll
        for (int j=0;j<4;++j)
          sum[mf][nf][j] += fmaxf(acc[mf][nf][j], 0.f);
  }
  __syncthreads();                     // all main-loop LDS reads done before reuse
  char* hT0 = pool + 24576;
  char* hT1 = hT0 + 8192;
  char* OP  = pool;                    // 16 KB free region for output staging
  #pragma unroll
  for (int mf=0; mf<2; ++mf)
    #pragma unroll
    for (int nf=0; nf<4; ++nf)
      #pragma unroll
      for (int j=0; j<4; ++j){
        int nloc = (wr<<5) + (mf<<4) + ((l>>4)<<2) + j;      // local n row (0..63)
        int e    = (wc<<6) + (nf<<4) + (l&15);               // d col (0..127)
        int n    = mt*64 + nloc;
        u16 hv = f2bf(sum[mf][nf][j] * all_mask[b*cN + n]);
        char* base = (e & 64) ? hT1 : hT0;
        *(u16*)(base + nloc*128 + (((e&63)*2) ^ ((nloc&7)<<4))) = hv;
      }
  if (layer == cL-1){
    __syncthreads();                   // hT panels complete
    char* gdst = (char*)(hfin + ((size_t)(s*cB + b)*cN + (size_t)mt*64)*cD);
    #pragma unroll
    for (int j=0;j<4;++j){
      int p = j*4096 + t*16;
      int nloc = p>>8, ebyte = p&255;
      char* hbase = (ebyte & 128) ? hT1 : hT0;
      int chunk = ebyte & 127;
      int4 v2 = *(const int4*)(hbase + nloc*128 + (chunk ^ ((nloc&7)<<4)));
      *(int4*)(gdst + (size_t)nloc*256 + ebyte) = v2;
    }
    return;
  }
  // fused next-layer k1
  char* W0 = pool + 40960;
  char* W1 = W0 + 16384;
  for (int r=0; r<3; ++r){
    __syncthreads();                                 // hT visible / prev W+OP reads done
    const u16* Wbase = WT + (size_t)(s*15 + (layer+1)*3 + r)*16384;
    stage16k(Wbase, 256, 0,   W0, w, l);
    stage16k(Wbase, 256, 128, W1, w, l);
    __syncthreads();
    f32x4 acc2[4][2];
    #pragma unroll
    for (int i=0;i<4;++i){ acc2[i][0]=f32x4{0,0,0,0}; acc2[i][1]=f32x4{0,0,0,0}; }
    mfma_tile<4,2>(W0, hT0, wr<<6, wc<<5, l, acc2);
    mfma_tile<4,2>(W1, hT1, wr<<6, wc<<5, l, acc2);
    const float* bias = (s ? critic_b : actor_b) + ((layer+1)*3 + r)*cD;
    #pragma unroll
    for (int mf=0; mf<4; ++mf)
      #pragma unroll
      for (int nf=0; nf<2; ++nf)
        #pragma unroll
        for (int j=0; j<4; ++j){
          int e   = (wr<<6) + (mf<<4) + ((l>>4)<<2) + j;
          int m64 = (wc<<5) + (nf<<4) + (l&15);
          *(u16*)(OP + e*128 + m64*2) = f2bf(acc2[mf][nf][j] + bias[e]);
        }
    __syncthreads();                                 // OP complete
    char* outB = (char*)(hwT_out + (size_t)((s*3+r)*cB + b)*cD*cN);
    flush16k(OP, outB, 1024, mt*128, t);
  }
}

// ================= pooling stage 1: partial sum/max over 32-row chunks =================
__global__ __launch_bounds__(256) void pool_part(const u16* __restrict__ xc, const float* __restrict__ cmask,
                                                 float* __restrict__ part){
  int blk = blockIdx.x;               // b*16 + c
  int b = blk >> 4, c = blk & 15;
  int t = threadIdx.x; int d = t & 127, nh = t >> 7;
  const u16* x = xc + ((size_t)b*cN + c*32 + nh*16)*cD;
  const float* cm = cmask + (size_t)b*cN + c*32 + nh*16;
  float sm = 0.f, mx = -3e38f;
  #pragma unroll
  for (int i=0;i<16;++i){
    float v = bf2f(x[(size_t)i*cD + d]);
    float m = cm[i];
    sm += v*m;
    mx = fmaxf(mx, v + (m==1.0f ? 0.f : NEGV));
  }
  __shared__ float s_sm[2][128], s_mx[2][128];
  s_sm[nh][d] = sm; s_mx[nh][d] = mx;
  __syncthreads();
  if (nh == 0){
    float* dst = part + ((size_t)b*16 + c)*256;
    dst[d]       = sm + s_sm[1][d];
    dst[128 + d] = fmaxf(mx, s_mx[1][d]);
  }
}

// ================= actor: end logits as MFMA GEMM (computes sc internally) =================
__global__ __launch_bounds__(256,2) void end_logits2(const u16* __restrict__ xa, const u16* __restrict__ WT,
                                                     const u16* __restrict__ Wc, const int* __restrict__ focus,
                                                     const float* __restrict__ be1,
                                                     const float* __restrict__ prob_mask, float* __restrict__ logits){
  __shared__ __align__(16) char smA[16384];
  __shared__ __align__(16) char smB[16384];
  __shared__ float s_start[128], sh_sc[128], sh_w2[128], rowsum[2][128];
  int blk = blockIdx.x;                // b*4 + nt
  int nt = blk & 3, b = blk >> 2;
  int t = threadIdx.x, w = t>>6, l = t&63, wr = w>>1, wc = w&1;
  if (t < 128){
    s_start[t] = bf2f(xa[((size_t)b*cN + focus[b])*cD + t]);
    sh_w2[t]   = bf2f(Wc[WOF_WE2 + t]);
  }
  __syncthreads();
  if (t < 128){
    float a = be1[t];
    #pragma unroll 4
    for (int k=0;k<128;++k) a += s_start[k]*bf2f(Wc[WOF_WE1 + k*cD + t]);
    sh_sc[t] = a;
  }
  const u16* Abase = xa + ((size_t)b*cN + (size_t)nt*128)*cD;
  const u16* Bbase = WT + (size_t)30*16384;
  f32x4 acc[4][4];
  #pragma unroll
  for (int i=0;i<4;++i){ acc[i][0]=f32x4{0,0,0,0}; acc[i][1]=f32x4{0,0,0,0}; acc[i][2]=f32x4{0,0,0,0}; acc[i][3]=f32x4{0,0,0,0}; }
  for (int kt=0; kt<2; ++kt){
    __syncthreads();
    stage16k(Abase, 256, kt*128, smA, w, l);
    stage16k(Bbase, 256, kt*128, smB, w, l);
    __syncthreads();
    mfma_tile<4,4>(smA, smB, wr<<6, wc<<6, l, acc);
  }
  float p[4][4];
  #pragma unroll
  for (int mf=0;mf<4;++mf)
    #pragma unroll
    for (int j=0;j<4;++j) p[mf][j] = 0.f;
  #pragma unroll
  for (int mf=0; mf<4; ++mf)
    #pragma unroll
    for (int nf=0; nf<4; ++nf){
      int e = (wc<<6) + (nf<<4) + (l&15);
      float scv = sh_sc[e], w2 = sh_w2[e];
      #pragma unroll
      for (int j=0; j<4; ++j)
        p[mf][j] += fmaxf(acc[mf][nf][j] + scv, 0.f) * w2;
    }
  #pragma unroll
  for (int mf=0; mf<4; ++mf)
    #pragma unroll
    for (int j=0; j<4; ++j){
      float v = p[mf][j];
      #pragma unroll
      for (int o=1;o<16;o<<=1) v += __shfl_xor(v, o, 64);
      if ((l&15)==0) rowsum[wc][(wr<<6) + (mf<<4) + ((l>>4)<<2) + j] = v;
    }
  __syncthreads();
  if (t < 128){
    int n = nt*128 + t;
    float pm = (prob_mask[b*cN + n]==1.0f) ? 0.f : NEGV;
    logits[b*cN + n] = rowsum[0][t] + rowsum[1][t] + pm;
  }
}

// ================= fused final heads: qvalue + end softmax/entropy + bond/stop =================
__global__ __launch_bounds__(128) void heads_final(const float* __restrict__ part, const u16* __restrict__ Wc,
                                                   const float* __restrict__ bq1, const float* __restrict__ bq2,
                                                   const float* __restrict__ logits, const int* __restrict__ action,
                                                   const u16* __restrict__ xa, const int* __restrict__ focus,
                                                   const float* __restrict__ bb1, const float* __restrict__ bs1,
                                                   float* __restrict__ out){
  int b = blockIdx.x, t = threadIdx.x;
  __shared__ float qin[256];
  __shared__ float sv[128], ev[128];
  __shared__ float redq[2], red5[5][2];
  __shared__ float HendSh;
  sv[t] = bf2f(xa[((size_t)b*cN + focus[b])*cD + t]);
  ev[t] = bf2f(xa[((size_t)b*cN + action[b*3])*cD + t]);
  float sm = 0.f, mx = -3e38f;
  #pragma unroll
  for (int c=0;c<16;++c){
    const float* src = part + ((size_t)b*16 + c)*256;
    sm += src[t];
    mx = fmaxf(mx, src[128 + t]);
  }
  qin[t] = sm; qin[128+t] = mx;
  __syncthreads();
  float acc = bq1[t];
  #pragma unroll 4
  for (int k=0; k<256; ++k) acc += qin[k]*bf2f(Wc[WOF_WQ1 + k*cD + t]);
  float hc = fmaxf(acc,0.f)*bf2f(Wc[WOF_WQ2 + t]);
  #pragma unroll
  for (int o=32;o>0;o>>=1) hc += __shfl_down(hc, o, 64);
  if ((t&63)==0) redq[t>>6] = hc;
  if (t < 64){
    float v[8];
    #pragma unroll
    for (int i=0;i<8;++i) v[i] = logits[b*cN + i*64 + t];
    float m = v[0];
    #pragma unroll
    for (int i=1;i<8;++i) m = fmaxf(m, v[i]);
    #pragma unroll
    for (int o=32;o>0;o>>=1) m = fmaxf(m, __shfl_xor(m, o, 64));
    float e[8]; float s = 0.f;
    #pragma unroll
    for (int i=0;i<8;++i){ e[i] = expf(v[i]-m); s += e[i]; }
    #pragma unroll
    for (int o=32;o>0;o>>=1) s += __shfl_xor(s, o, 64);
    float lns = logf(s);
    float pl = 0.f;
    #pragma unroll
    for (int i=0;i<8;++i){ float p = e[i]/s; pl += p*((v[i]-m) - lns); }
    #pragma unroll
    for (int o=32;o>0;o>>=1) pl += __shfl_xor(pl, o, 64);
    int idx = action[b*3 + 0];
    if (t == (idx & 63)){
      float pe = 0.f;
      #pragma unroll
      for (int i=0;i<8;++i) if ((idx>>6)==i) pe = e[i];
      out[b*3 + 0] = pe / s;
    }
    if (t == 0) HendSh = -pl;
  }
  __syncthreads();
  float ab = bb1[t], as_ = bs1[t];
  #pragma unroll 4
  for (int k=0;k<128;++k){ float svk = sv[k]; ab += svk*bf2f(Wc[WOF_WB1 + k*cD + t]); as_ += svk*bf2f(Wc[WOF_WS1 + k*cD + t]); }
  #pragma unroll 4
  for (int k=0;k<128;++k) ab += ev[k]*bf2f(Wc[WOF_WB1 + (128+k)*cD + t]);
  float hb = fmaxf(ab,0.f), hs = fmaxf(as_,0.f);
  float r0 = hb*bf2f(Wc[WOF_WB2 + t*3+0]);
  float r1 = hb*bf2f(Wc[WOF_WB2 + t*3+1]);
  float r2 = hb*bf2f(Wc[WOF_WB2 + t*3+2]);
  float r3 = hs*bf2f(Wc[WOF_WS2 + t*2+0]);
  float r4 = hs*bf2f(Wc[WOF_WS2 + t*2+1]);
  #pragma unroll
  for (int o=32;o>0;o>>=1){
    r0 += __shfl_xor(r0,o,64); r1 += __shfl_xor(r1,o,64); r2 += __shfl_xor(r2,o,64);
    r3 += __shfl_xor(r3,o,64); r4 += __shfl_xor(r4,o,64);
  }
  if ((t&63)==0){ int wid=t>>6; red5[0][wid]=r0; red5[1][wid]=r1; red5[2][wid]=r2; red5[3][wid]=r3; red5[4][wid]=r4; }
  __syncthreads();
  if (t==0){
    out[128 + b] = redq[0] + redq[1] + bq2[0];
    auto xlx = [](float p){ return p > 0.f ? p*logf(p) : 0.f; };
    float bl0=red5[0][0]+red5[0][1], bl1=red5[1][0]+red5[1][1], bl2=red5[2][0]+red5[2][1];
    float sl0=red5[3][0]+red5[3][1], sl1=red5[4][0]+red5[4][1];
    float m = fmaxf(fmaxf(bl0,bl1),bl2);
    float e0=expf(bl0-m), e1=expf(bl1-m), e2=expf(bl2-m); float S=e0+e1+e2;
    float p0=e0/S, p1=e1/S, p2=e2/S;
    float Hb = -(xlx(p0) + xlx(p1) + xlx(p2));
    int a1 = action[b*3+1];
    out[b*3+1] = (a1==0)?p0:((a1==1)?p1:p2);
    float ms = fmaxf(sl0,sl1);
    float f0=expf(sl0-ms), f1=expf(sl1-ms); float T=f0+f1;
    float q0=f0/T, q1=f1/T;
    float Hs = -(xlx(q0) + xlx(q1));
    int a2 = action[b*3+2];
    out[b*3+2] = (a2==0)?q0:q1;
    out[96+b] = HendSh + Hb + Hs;
  }
}

// ================= launcher =================
extern "C" void kernel_launch(void* const* d_in, const int* in_sizes, int n_in,
                              void* d_out, int out_size, void* d_ws, size_t ws_size,
                              hipStream_t stream){
  const float* fatoms      = (const float*)d_in[0];
  const float* adj         = (const float*)d_in[1];
  const float* all_mask    = (const float*)d_in[2];
  const float* current_mask= (const float*)d_in[3];
  const float* prob_mask   = (const float*)d_in[4];
  const int*   focus       = (const int*)d_in[5];
  const int*   action      = (const int*)d_in[6];
  const float* actor_b     = (const float*)d_in[10];
  const float* critic_b    = (const float*)d_in[12];
  const float* be1         = (const float*)d_in[14];
  const float* bb1         = (const float*)d_in[17];
  const float* bs1         = (const float*)d_in[20];
  const float* bq1         = (const float*)d_in[23];
  const float* bq2         = (const float*)d_in[25];

  char* ws = (char*)d_ws;
  size_t o = 0;
  u16* adjT = (u16*)(ws + o);  o += (size_t)3*cB*cN*cN*2;        // 50.3 MB (written by k2f_l0)
  u16* WT   = (u16*)(ws + o);  o += (size_t)31*16384*2;          //  1.0 MB
  u16* hbuf = (u16*)(ws + o);  o += (size_t)2*2*cB*cN*cD*2;      // 16.8 MB (phase0=h0, phase1=hfin)
  u16* hwT0 = (u16*)(ws + o);  o += (size_t)2*3*cB*cD*cN*2;      // 25.2 MB
  u16* hwT1 = (u16*)(ws + o);  o += (size_t)2*3*cB*cD*cN*2;      // 25.2 MB
  u16* Wcan = (u16*)(ws + o);  o += (size_t)WTOTAL*2;
  float* part   = (float*)(ws + o); o += (size_t)cB*16*256*4;
  float* logits = (float*)(ws + o); o += (size_t)cB*cN*4;
  float* out = (float*)d_out;

  WPtrs wp;
  wp.p[0]=d_in[7];  wp.p[1]=d_in[8];  wp.p[2]=d_in[9];  wp.p[3]=d_in[11];
  wp.p[4]=d_in[13]; wp.p[5]=d_in[15]; wp.p[6]=d_in[16]; wp.p[7]=d_in[18];
  wp.p[8]=d_in[19]; wp.p[9]=d_in[21]; wp.p[10]=d_in[22]; wp.p[11]=d_in[24];

  canon_w<<<dim3((WTOTAL+255)/256), dim3(256), 0, stream>>>(wp, Wcan);
  prep_w<<<dim3(31), dim3(256), 0, stream>>>(Wcan, WT);
  emb<<<dim3(2*cB*cN), dim3(128), 0, stream>>>(fatoms, Wcan, hbuf);

  const size_t hstride = (size_t)2*cB*cN*cD;
  u16* hfin = hbuf + hstride;
  k1_hw<<<dim3(768), dim3(256), 0, stream>>>(WT, hbuf, actor_b, critic_b, hwT0, 0);
  k2f_l0<<<dim3(512), dim3(256), 0, stream>>>(adj, adjT, hwT0, hwT1, all_mask, WT, actor_b, critic_b);
  for (int l=1; l<cL; ++l){
    u16* win  = (l&1) ? hwT1 : hwT0;
    u16* wout = (l&1) ? hwT0 : hwT1;
    k2f_ln<<<dim3(512), dim3(256), 0, stream>>>(adjT, win, wout, all_mask, WT, actor_b, critic_b, hfin, l);
  }
  const u16* xa = hfin;
  const u16* xc = hfin + (size_t)cB*cN*cD;

  end_logits2<<<dim3(cB*4), dim3(256), 0, stream>>>(xa, WT, Wcan, focus, be1, prob_mask, logits);
  pool_part<<<dim3(cB*16), dim3(256), 0, stream>>>(xc, current_mask, part);
  heads_final<<<dim3(cB), dim3(128), 0, stream>>>(part, Wcan, bq1, bq2, logits, action, xa, focus, bb1, bs1, out);
}

// Round 14
// 250.025 us; speedup vs baseline: 1.0527x; 1.0041x over previous
//
#include <hip/hip_runtime.h>
#include <cstdint>
#include <cstddef>

typedef unsigned short u16;
typedef __bf16 bfx8 __attribute__((ext_vector_type(8)));
typedef float f32x4 __attribute__((ext_vector_type(4)));

#define NEGV -10000000.0f
constexpr int cB = 32, cN = 512, cD = 128, cF = 20, cL = 5;

__device__ __forceinline__ float bf2f(u16 h){ unsigned u = ((unsigned)h)<<16; return __builtin_bit_cast(float,u); }
__device__ __forceinline__ u16 f2bf(float f){ unsigned u = __builtin_bit_cast(unsigned,f); return (u16)((u + 0x7fffu + ((u>>16)&1u))>>16); }

// ===== canonical weight buffer layout (element offsets, bf16) =====
constexpr int WOF_EMB  = 0;
constexpr int WOF_CEMB = 2560;
constexpr int WOF_AW   = 5120;
constexpr int WOF_CW   = 250880;
constexpr int WOF_WE1  = 496640;
constexpr int WOF_WE2  = 529408;
constexpr int WOF_WB1  = 529536;
constexpr int WOF_WB2  = 562304;
constexpr int WOF_WS1  = 562688;
constexpr int WOF_WS2  = 579072;
constexpr int WOF_WQ1  = 579328;
constexpr int WOF_WQ2  = 612096;
constexpr int WTOTAL   = 612224;

struct WPtrs { const void* p[12]; };

// ================= canonicalize weights to bf16 (self-detecting dtype) =================
__global__ __launch_bounds__(256) void canon_w(WPtrs wp, u16* __restrict__ Wc){
  __shared__ int s_flag;
  int t = threadIdx.x;
  if (t == 0) s_flag = 0;
  __syncthreads();
  const u16* probe = (const u16*)wp.p[2];
  int big = 0;
  #pragma unroll
  for (int i=0;i<2;++i){
    float a = fabsf(bf2f(probe[i*256 + t]));
    if (!(a < 1e10f)) big = 1;
  }
  if (__any(big)) s_flag = 1;       // benign race: only ever sets 1
  __syncthreads();
  int flag = s_flag;
  int i = blockIdx.x*256 + t;
  if (i >= WTOTAL) return;
  constexpr int offs[13] = {WOF_EMB, WOF_CEMB, WOF_AW, WOF_CW, WOF_WE1, WOF_WE2,
                            WOF_WB1, WOF_WB2, WOF_WS1, WOF_WS2, WOF_WQ1, WOF_WQ2, WTOTAL};
  int a = 0;
  #pragma unroll
  for (int k = 1; k < 12; ++k) if (i >= offs[k]) a = k;
  int off = i - offs[a];
  const void* p = wp.p[a];
  Wc[i] = flag ? f2bf(((const float*)p)[off]) : ((const u16*)p)[off];
}

// ================= prep: transpose weights; blk 0..29 GCN W, blk 30 = We1 bottom =================
__global__ __launch_bounds__(256) void prep_w(const u16* __restrict__ Wc, u16* __restrict__ WT){
  __shared__ u16 sh[128*129];
  int blk = blockIdx.x;
  const u16* in;
  if (blk < 30){
    int s = blk/15; int lr = blk%15;
    in = Wc + (s ? WOF_CW : WOF_AW) + (size_t)lr*16384;
  } else {
    in = Wc + WOF_WE1 + 128*cD;           // We1 bottom half [k=128..255][e]
  }
  u16* out = WT + (size_t)blk*16384;
  int t = threadIdx.x;
  #pragma unroll 4
  for (int i=0;i<64;++i){ int idx=i*256+t; int d=idx>>7, e=idx&127; sh[e*129+d]=in[idx]; }
  __syncthreads();
  #pragma unroll 4
  for (int i=0;i<64;++i){ int idx=i*256+t; int e=idx>>7, d=idx&127; out[idx]=sh[e*129+d]; }
}

// ================= emb: h0 = relu(fatoms @ W) bf16, both stacks =================
__global__ __launch_bounds__(128) void emb(const float* __restrict__ fatoms, const u16* __restrict__ Wc, u16* __restrict__ h0){
  int row = blockIdx.x;
  int s = row >> 14; int bn = row & 16383;
  __shared__ float fa[cF];
  int t = threadIdx.x;
  if (t < cF) fa[t] = fatoms[(size_t)bn*cF + t];
  __syncthreads();
  const u16* W = Wc + (s ? WOF_CEMB : WOF_EMB);
  float acc = 0.f;
  #pragma unroll
  for (int f=0; f<cF; ++f) acc += fa[f]*bf2f(W[f*cD + t]);
  h0[((size_t)s*cB*cN + bn)*cD + t] = f2bf(fmaxf(acc,0.f));
}

// ================= MFMA tile helpers (m97 recipe) =================
__device__ __forceinline__ void stage16k(const u16* gbase, int ldaB, int ktB, char* sm, int w, int l){
  #pragma unroll
  for (int i=0;i<4;++i){
    int c = (w<<2) + i;
    int row = (c<<3) + (l>>3);
    const char* src = (const char*)gbase + (size_t)row*ldaB + ktB + (((l&7)^(row&7))<<4);
    __builtin_amdgcn_global_load_lds((const __attribute__((address_space(1))) void*)src,
                                     (__attribute__((address_space(3))) void*)(sm + (c<<10)), 16, 0, 0);
  }
}
__device__ __forceinline__ void stage8k(const u16* gbase, int ldaB, int ktB, char* sm, int w, int l){
  #pragma unroll
  for (int i=0;i<2;++i){
    int c = (w<<1) + i;
    int row = (c<<3) + (l>>3);
    const char* src = (const char*)gbase + (size_t)row*ldaB + ktB + (((l&7)^(row&7))<<4);
    __builtin_amdgcn_global_load_lds((const __attribute__((address_space(1))) void*)src,
                                     (__attribute__((address_space(3))) void*)(sm + (c<<10)), 16, 0, 0);
  }
}
__device__ __forceinline__ bfx8 readfrag(const char* sm, int row, int kk, int l){
  int col = ((kk<<6) + ((l>>4)<<4)) ^ ((row&7)<<4);
  return *(const bfx8*)(sm + row*128 + col);
}
template<int MF,int NF>
__device__ __forceinline__ void mfma_tile(const char* A, const char* Bm, int ra, int rb, int l, f32x4 (&acc)[MF][NF]){
  #pragma unroll
  for (int kk=0; kk<2; ++kk){
    bfx8 af[MF], bv[NF];
    #pragma unroll
    for (int f=0; f<MF; ++f) af[f] = readfrag(A,  ra+(f<<4)+(l&15), kk, l);
    #pragma unroll
    for (int f=0; f<NF; ++f) bv[f] = readfrag(Bm, rb+(f<<4)+(l&15), kk, l);
    #pragma unroll
    for (int mf=0; mf<MF; ++mf)
      #pragma unroll
      for (int nf=0; nf<NF; ++nf)
        acc[mf][nf] = __builtin_amdgcn_mfma_f32_16x16x32_bf16(af[mf], bv[nf], acc[mf][nf], 0,0,0);
  }
}
// coalesced panel flush: 16KB LDS panel [128 rows][128B] -> global rows of ld=ldB at
// byte col base colB. Per instruction j, lanes cover contiguous 4KB (dense 128B rows).
__device__ __forceinline__ void flush16k(const char* P, char* gbase, int ldB, int colB, int t){
  #pragma unroll
  for (int j=0;j<4;++j){
    int p = j*4096 + t*16;
    int e = p>>7, col = p&127;
    int4 v = *(const int4*)(P + p);
    *(int4*)(gbase + (size_t)e*ldB + colB + col) = v;
  }
}

// ================= K1 (layer 0 only): hw^T = W^T h + b =================
// XCD-aligned decode: all 24 blocks of batch b land on XCD b&7, matching the
// consumer (k2f_l0) mapping so hwT0 panels are read from the producing XCD's L2.
__global__ __launch_bounds__(256,2) void k1_hw(const u16* __restrict__ WT, const u16* __restrict__ h,
                                               const float* __restrict__ actor_b, const float* __restrict__ critic_b,
                                               u16* __restrict__ hwT, int layer){
  __shared__ __align__(16) char smA[16384];
  __shared__ __align__(16) char smB[16384];
  int blk = blockIdx.x;                       // 768 blocks
  int xcd = blk & 7; int slot = blk >> 3;     // 96 slots
  int b = (slot & 3)*8 + xcd;                 // b&7 == xcd
  int rest = slot >> 2;                       // [0,24): s*12 + r*4 + nt
  int s = rest/12; int rr = rest%12; int r = rr>>2; int nt = rr&3;
  int t = threadIdx.x, w = t>>6, l = t&63, wr = w>>1, wc = w&1;
  const u16* Abase = WT + (size_t)(s*15 + layer*3 + r)*16384;
  const u16* Bbase = h + ((size_t)s*cB*cN + (size_t)b*cN + (size_t)nt*128)*cD;
  f32x4 acc[4][4];
  #pragma unroll
  for (int i=0;i<4;++i){ acc[i][0]=f32x4{0,0,0,0}; acc[i][1]=f32x4{0,0,0,0}; acc[i][2]=f32x4{0,0,0,0}; acc[i][3]=f32x4{0,0,0,0}; }
  for (int kt=0; kt<2; ++kt){
    __syncthreads();
    stage16k(Abase, 256, kt*128, smA, w, l);
    stage16k(Bbase, 256, kt*128, smB, w, l);
    __syncthreads();
    mfma_tile<4,4>(smA, smB, wr<<6, wc<<6, l, acc);
  }
  const float* bias = (s ? critic_b : actor_b) + (layer*3 + r)*cD;
  __syncthreads();                       // all waves done reading smA/smB
  char* OPh = wc ? smB : smA;
  #pragma unroll
  for (int mf=0; mf<4; ++mf)
    #pragma unroll
    for (int nf=0; nf<4; ++nf)
      #pragma unroll
      for (int j=0; j<4; ++j){
        int e  = (wr<<6) + (mf<<4) + ((l>>4)<<2) + j;
        int mh = (nf<<4) + (l&15);
        *(u16*)(OPh + e*128 + mh*2) = f2bf(acc[mf][nf][j] + bias[e]);
      }
  __syncthreads();
  char* outB = (char*)(hwT + (size_t)((s*3+r)*cB + b)*cD*cN);
  flush16k(smA, outB, 1024, nt*256 + 0,   t);
  flush16k(smB, outB, 1024, nt*256 + 128, t);
}

// ================= K2F layer 0: 64x128 tiles, 512 blocks, adj-direct pipeline =================
__global__ __launch_bounds__(256,2) void k2f_l0(const float* __restrict__ adj, u16* __restrict__ adjT,
                                                const u16* __restrict__ hwT_in, u16* __restrict__ hwT_out,
                                                const float* __restrict__ all_mask, const u16* __restrict__ WT,
                                                const float* __restrict__ actor_b, const float* __restrict__ critic_b){
  __shared__ __align__(16) char pool[73728];
  int blk = blockIdx.x;                          // 512 blocks
  int xcd = blk & 7; int slot = blk >> 3;
  int b = (slot>>4)*8 + xcd;
  int rest = slot & 15; int s = rest>>3; int mt = rest&7;
  int t = threadIdx.x, w = t>>6, l = t&63, wr = w>>1, wc = w&1;
  const u16* hwB = hwT_in + (size_t)(s*3*cB + b)*cD*cN;
  const size_t hwRs = (size_t)cB*cD*cN;
  f32x4 sum[2][4];
  #pragma unroll
  for (int i=0;i<2;++i)
    #pragma unroll
    for (int j=0;j<4;++j) sum[i][j]=f32x4{0,0,0,0};

  f32x4 a3[3][2][4];
  #pragma unroll
  for (int r=0;r<3;++r)
    #pragma unroll
    for (int i=0;i<2;++i)
      #pragma unroll
      for (int j=0;j<4;++j) a3[r][i][j]=f32x4{0,0,0,0};
  const int nl  = t>>2;
  const int m8  = (t&3)*2;
  const float* asrc = adj + ((size_t)(b*cN + mt*64 + nl)*cN + m8*8)*3;
  float4 v[12];
  #pragma unroll
  for (int q=0;q<12;++q) v[q] = ((const float4*)asrc)[q];      // prologue: kt=0
  for (int kt=0; kt<8; ++kt){
    __builtin_amdgcn_s_barrier();
    __builtin_amdgcn_sched_barrier(0);
    stage16k(hwB,        1024, kt*128, pool+24576, w, l);
    stage16k(hwB+hwRs,   1024, kt*128, pool+40960, w, l);
    stage16k(hwB+2*hwRs, 1024, kt*128, pool+57344, w, l);
    __builtin_amdgcn_sched_barrier(0);
    const float* vf = (const float*)v;
    __align__(16) u16 o[2][3][8];
    #pragma unroll
    for (int i=0;i<2;++i)
      #pragma unroll
      for (int r=0;r<3;++r)
        #pragma unroll
        for (int k=0;k<8;++k) o[i][r][k] = f2bf(vf[i*24 + k*3 + r]);
    #pragma unroll
    for (int i=0;i<2;++i){
      int m8i = m8 + i;
      #pragma unroll
      for (int r=0;r<3;++r)
        *(int4*)(pool + r*8192 + nl*128 + ((m8i*16) ^ ((nl&7)<<4))) = *(const int4*)&o[i][r][0];
    }
    if (kt < 7){
      const float* sp = asrc + (size_t)(kt+1)*64*3;
      #pragma unroll
      for (int q=0;q<12;++q) v[q] = ((const float4*)sp)[q];
    }
    __builtin_amdgcn_sched_barrier(0);
    if (kt < 7) asm volatile("s_waitcnt vmcnt(12)" ::: "memory");
    else        asm volatile("s_waitcnt vmcnt(0)"  ::: "memory");
    asm volatile("s_waitcnt lgkmcnt(0)" ::: "memory");
    __builtin_amdgcn_sched_barrier(0);
    __builtin_amdgcn_s_barrier();
    __builtin_amdgcn_sched_barrier(0);
    if (s == 0){
      #pragma unroll
      for (int r=0;r<3;++r){
        char* gb = (char*)adjT + (((size_t)(r*cB + b)*cN + (size_t)mt*64)*cN + (size_t)kt*64)*2;
        #pragma unroll
        for (int j=0;j<2;++j){
          int p = j*4096 + t*16;
          int n2 = p>>7, chunk = p&127;
          int4 val = *(const int4*)(pool + r*8192 + n2*128 + (chunk ^ ((n2&7)<<4)));
          *(int4*)(gb + (size_t)n2*1024 + chunk) = val;
        }
      }
    }
    #pragma unroll
    for (int r=0;r<3;++r)
      mfma_tile<2,4>(pool + r*8192, pool + 24576 + r*16384, wr<<5, wc<<6, l, a3[r]);
  }
  #pragma unroll
  for (int r=0;r<3;++r)
    #pragma unroll
    for (int mf=0;mf<2;++mf)
      #pragma unroll
      for (int nf=0;nf<4;++nf)
        #pragma unroll
        for (int j=0;j<4;++j)
          sum[mf][nf][j] += fmaxf(a3[r][mf][nf][j], 0.f);
  __syncthreads();
  char* hT0 = pool;
  char* hT1 = pool + 8192;
  char* OP  = pool + 57344;
  #pragma unroll
  for (int mf=0; mf<2; ++mf)
    #pragma unroll
    for (int nf=0; nf<4; ++nf)
      #pragma unroll
      for (int j=0; j<4; ++j){
        int nloc = (wr<<5) + (mf<<4) + ((l>>4)<<2) + j;
        int e    = (wc<<6) + (nf<<4) + (l&15);
        int n    = mt*64 + nloc;
        u16 hv = f2bf(sum[mf][nf][j] * all_mask[b*cN + n]);
        char* base = (e & 64) ? hT1 : hT0;
        *(u16*)(base + nloc*128 + (((e&63)*2) ^ ((nloc&7)<<4))) = hv;
      }
  char* W0 = pool + 24576;
  char* W1 = W0 + 16384;
  for (int r=0; r<3; ++r){
    __syncthreads();
    const u16* Wbase = WT + (size_t)(s*15 + 1*3 + r)*16384;       // layer+1 = 1
    stage16k(Wbase, 256, 0,   W0, w, l);
    stage16k(Wbase, 256, 128, W1, w, l);
    __syncthreads();
    f32x4 acc2[4][2];
    #pragma unroll
    for (int i=0;i<4;++i){ acc2[i][0]=f32x4{0,0,0,0}; acc2[i][1]=f32x4{0,0,0,0}; }
    mfma_tile<4,2>(W0, hT0, wr<<6, wc<<5, l, acc2);
    mfma_tile<4,2>(W1, hT1, wr<<6, wc<<5, l, acc2);
    const float* bias = (s ? critic_b : actor_b) + (1*3 + r)*cD;
    #pragma unroll
    for (int mf=0; mf<4; ++mf)
      #pragma unroll
      for (int nf=0; nf<2; ++nf)
        #pragma unroll
        for (int j=0; j<4; ++j){
          int e   = (wr<<6) + (mf<<4) + ((l>>4)<<2) + j;
          int m64 = (wc<<5) + (nf<<4) + (l&15);
          *(u16*)(OP + e*128 + m64*2) = f2bf(acc2[mf][nf][j] + bias[e]);
        }
    __syncthreads();
    char* outB = (char*)(hwT_out + (size_t)((s*3+r)*cB + b)*cD*cN);
    flush16k(OP, outB, 1024, mt*128, t);
  }
}

// ================= K2F layers 1..4: 64x128 tiles, 512 blocks = 2/CU =================
__global__ __launch_bounds__(256,2) void k2f_ln(const u16* __restrict__ adjT,
                                                const u16* __restrict__ hwT_in, u16* __restrict__ hwT_out,
                                                const float* __restrict__ all_mask, const u16* __restrict__ WT,
                                                const float* __restrict__ actor_b, const float* __restrict__ critic_b,
                                                u16* __restrict__ hfin, int layer){
  __shared__ __align__(16) char pool[73728];
  int blk = blockIdx.x;                          // 512 blocks
  int xcd = blk & 7; int slot = blk >> 3;
  int b = (slot>>4)*8 + xcd;
  int rest = slot & 15; int s = rest>>3; int mt = rest&7;
  int t = threadIdx.x, w = t>>6, l = t&63, wr = w>>1, wc = w&1;
  const u16* hwB = hwT_in + (size_t)(s*3*cB + b)*cD*cN;
  const size_t hwRs = (size_t)cB*cD*cN;
  f32x4 sum[2][4];
  #pragma unroll
  for (int i=0;i<2;++i)
    #pragma unroll
    for (int j=0;j<4;++j) sum[i][j]=f32x4{0,0,0,0};
  // LDS: smA at 0 (8K), smB at 8192 (16K)
  const u16* adjB = adjT + ((size_t)b*cN + (size_t)mt*64)*cN;
  const size_t adjRs = (size_t)cB*cN*cN;
  for (int r=0;r<3;++r){
    f32x4 acc[2][4];
    #pragma unroll
    for (int i=0;i<2;++i)
      #pragma unroll
      for (int j=0;j<4;++j) acc[i][j]=f32x4{0,0,0,0};
    for (int kt=0;kt<8;++kt){
      __syncthreads();
      stage8k (adjB + (size_t)r*adjRs, 1024, kt*128, pool, w, l);
      stage16k(hwB  + (size_t)r*hwRs,  1024, kt*128, pool+8192, w, l);
      __syncthreads();
      mfma_tile<2,4>(pool, pool+8192, wr<<5, wc<<6, l, acc);
    }
    #pragma unroll
    for (int mf=0;mf<2;++mf)
      #pragma unroll
      for (int nf=0;nf<4;++nf)
        #pragma unroll
        for (int j=0;j<4;++j)
          sum[mf][nf][j] += fmaxf(acc[mf][nf][j], 0.f);
  }
  __syncthreads();                     // all main-loop LDS reads done before reuse
  char* hT0 = pool + 24576;
  char* hT1 = hT0 + 8192;
  char* OP  = pool;                    // 16 KB free region for output staging
  #pragma unroll
  for (int mf=0; mf<2; ++mf)
    #pragma unroll
    for (int nf=0; nf<4; ++nf)
      #pragma unroll
      for (int j=0; j<4; ++j){
        int nloc = (wr<<5) + (mf<<4) + ((l>>4)<<2) + j;      // local n row (0..63)
        int e    = (wc<<6) + (nf<<4) + (l&15);               // d col (0..127)
        int n    = mt*64 + nloc;
        u16 hv = f2bf(sum[mf][nf][j] * all_mask[b*cN + n]);
        char* base = (e & 64) ? hT1 : hT0;
        *(u16*)(base + nloc*128 + (((e&63)*2) ^ ((nloc&7)<<4))) = hv;
      }
  if (layer == cL-1){
    __syncthreads();                   // hT panels complete
    char* gdst = (char*)(hfin + ((size_t)(s*cB + b)*cN + (size_t)mt*64)*cD);
    #pragma unroll
    for (int j=0;j<4;++j){
      int p = j*4096 + t*16;
      int nloc = p>>8, ebyte = p&255;
      char* hbase = (ebyte & 128) ? hT1 : hT0;
      int chunk = ebyte & 127;
      int4 v2 = *(const int4*)(hbase + nloc*128 + (chunk ^ ((nloc&7)<<4)));
      *(int4*)(gdst + (size_t)nloc*256 + ebyte) = v2;
    }
    return;
  }
  // fused next-layer k1
  char* W0 = pool + 40960;
  char* W1 = W0 + 16384;
  for (int r=0; r<3; ++r){
    __syncthreads();                                 // hT visible / prev W+OP reads done
    const u16* Wbase = WT + (size_t)(s*15 + (layer+1)*3 + r)*16384;
    stage16k(Wbase, 256, 0,   W0, w, l);
    stage16k(Wbase, 256, 128, W1, w, l);
    __syncthreads();
    f32x4 acc2[4][2];
    #pragma unroll
    for (int i=0;i<4;++i){ acc2[i][0]=f32x4{0,0,0,0}; acc2[i][1]=f32x4{0,0,0,0}; }
    mfma_tile<4,2>(W0, hT0, wr<<6, wc<<5, l, acc2);
    mfma_tile<4,2>(W1, hT1, wr<<6, wc<<5, l, acc2);
    const float* bias = (s ? critic_b : actor_b) + ((layer+1)*3 + r)*cD;
    #pragma unroll
    for (int mf=0; mf<4; ++mf)
      #pragma unroll
      for (int nf=0; nf<2; ++nf)
        #pragma unroll
        for (int j=0; j<4; ++j){
          int e   = (wr<<6) + (mf<<4) + ((l>>4)<<2) + j;
          int m64 = (wc<<5) + (nf<<4) + (l&15);
          *(u16*)(OP + e*128 + m64*2) = f2bf(acc2[mf][nf][j] + bias[e]);
        }
    __syncthreads();                                 // OP complete
    char* outB = (char*)(hwT_out + (size_t)((s*3+r)*cB + b)*cD*cN);
    flush16k(OP, outB, 1024, mt*128, t);
  }
}

// ================= pooling stage 1: partial sum/max over 32-row chunks =================
__global__ __launch_bounds__(256) void pool_part(const u16* __restrict__ xc, const float* __restrict__ cmask,
                                                 float* __restrict__ part){
  int blk = blockIdx.x;               // b*16 + c
  int b = blk >> 4, c = blk & 15;
  int t = threadIdx.x; int d = t & 127, nh = t >> 7;
  const u16* x = xc + ((size_t)b*cN + c*32 + nh*16)*cD;
  const float* cm = cmask + (size_t)b*cN + c*32 + nh*16;
  float sm = 0.f, mx = -3e38f;
  #pragma unroll
  for (int i=0;i<16;++i){
    float v = bf2f(x[(size_t)i*cD + d]);
    float m = cm[i];
    sm += v*m;
    mx = fmaxf(mx, v + (m==1.0f ? 0.f : NEGV));
  }
  __shared__ float s_sm[2][128], s_mx[2][128];
  s_sm[nh][d] = sm; s_mx[nh][d] = mx;
  __syncthreads();
  if (nh == 0){
    float* dst = part + ((size_t)b*16 + c)*256;
    dst[d]       = sm + s_sm[1][d];
    dst[128 + d] = fmaxf(mx, s_mx[1][d]);
  }
}

// ================= actor: end logits as MFMA GEMM (computes sc internally) =================
__global__ __launch_bounds__(256,2) void end_logits2(const u16* __restrict__ xa, const u16* __restrict__ WT,
                                                     const u16* __restrict__ Wc, const int* __restrict__ focus,
                                                     const float* __restrict__ be1,
                                                     const float* __restrict__ prob_mask, float* __restrict__ logits){
  __shared__ __align__(16) char smA[16384];
  __shared__ __align__(16) char smB[16384];
  __shared__ float s_start[128], sh_sc[128], sh_w2[128], rowsum[2][128];
  int blk = blockIdx.x;                // b*4 + nt
  int nt = blk & 3, b = blk >> 2;
  int t = threadIdx.x, w = t>>6, l = t&63, wr = w>>1, wc = w&1;
  if (t < 128){
    s_start[t] = bf2f(xa[((size_t)b*cN + focus[b])*cD + t]);
    sh_w2[t]   = bf2f(Wc[WOF_WE2 + t]);
  }
  __syncthreads();
  if (t < 128){
    float a = be1[t];
    #pragma unroll 4
    for (int k=0;k<128;++k) a += s_start[k]*bf2f(Wc[WOF_WE1 + k*cD + t]);
    sh_sc[t] = a;
  }
  const u16* Abase = xa + ((size_t)b*cN + (size_t)nt*128)*cD;
  const u16* Bbase = WT + (size_t)30*16384;
  f32x4 acc[4][4];
  #pragma unroll
  for (int i=0;i<4;++i){ acc[i][0]=f32x4{0,0,0,0}; acc[i][1]=f32x4{0,0,0,0}; acc[i][2]=f32x4{0,0,0,0}; acc[i][3]=f32x4{0,0,0,0}; }
  for (int kt=0; kt<2; ++kt){
    __syncthreads();
    stage16k(Abase, 256, kt*128, smA, w, l);
    stage16k(Bbase, 256, kt*128, smB, w, l);
    __syncthreads();
    mfma_tile<4,4>(smA, smB, wr<<6, wc<<6, l, acc);
  }
  float p[4][4];
  #pragma unroll
  for (int mf=0;mf<4;++mf)
    #pragma unroll
    for (int j=0;j<4;++j) p[mf][j] = 0.f;
  #pragma unroll
  for (int mf=0; mf<4; ++mf)
    #pragma unroll
    for (int nf=0; nf<4; ++nf){
      int e = (wc<<6) + (nf<<4) + (l&15);
      float scv = sh_sc[e], w2 = sh_w2[e];
      #pragma unroll
      for (int j=0; j<4; ++j)
        p[mf][j] += fmaxf(acc[mf][nf][j] + scv, 0.f) * w2;
    }
  #pragma unroll
  for (int mf=0; mf<4; ++mf)
    #pragma unroll
    for (int j=0; j<4; ++j){
      float v = p[mf][j];
      #pragma unroll
      for (int o=1;o<16;o<<=1) v += __shfl_xor(v, o, 64);
      if ((l&15)==0) rowsum[wc][(wr<<6) + (mf<<4) + ((l>>4)<<2) + j] = v;
    }
  __syncthreads();
  if (t < 128){
    int n = nt*128 + t;
    float pm = (prob_mask[b*cN + n]==1.0f) ? 0.f : NEGV;
    logits[b*cN + n] = rowsum[0][t] + rowsum[1][t] + pm;
  }
}

// ================= fused final heads: qvalue + end softmax/entropy + bond/stop =================
__global__ __launch_bounds__(128) void heads_final(const float* __restrict__ part, const u16* __restrict__ Wc,
                                                   const float* __restrict__ bq1, const float* __restrict__ bq2,
                                                   const float* __restrict__ logits, const int* __restrict__ action,
                                                   const u16* __restrict__ xa, const int* __restrict__ focus,
                                                   const float* __restrict__ bb1, const float* __restrict__ bs1,
                                                   float* __restrict__ out){
  int b = blockIdx.x, t = threadIdx.x;
  __shared__ float qin[256];
  __shared__ float sv[128], ev[128];
  __shared__ float redq[2], red5[5][2];
  __shared__ float HendSh;
  sv[t] = bf2f(xa[((size_t)b*cN + focus[b])*cD + t]);
  ev[t] = bf2f(xa[((size_t)b*cN + action[b*3])*cD + t]);
  float sm = 0.f, mx = -3e38f;
  #pragma unroll
  for (int c=0;c<16;++c){
    const float* src = part + ((size_t)b*16 + c)*256;
    sm += src[t];
    mx = fmaxf(mx, src[128 + t]);
  }
  qin[t] = sm; qin[128+t] = mx;
  __syncthreads();
  float acc = bq1[t];
  #pragma unroll 4
  for (int k=0; k<256; ++k) acc += qin[k]*bf2f(Wc[WOF_WQ1 + k*cD + t]);
  float hc = fmaxf(acc,0.f)*bf2f(Wc[WOF_WQ2 + t]);
  #pragma unroll
  for (int o=32;o>0;o>>=1) hc += __shfl_down(hc, o, 64);
  if ((t&63)==0) redq[t>>6] = hc;
  if (t < 64){
    float v[8];
    #pragma unroll
    for (int i=0;i<8;++i) v[i] = logits[b*cN + i*64 + t];
    float m = v[0];
    #pragma unroll
    for (int i=1;i<8;++i) m = fmaxf(m, v[i]);
    #pragma unroll
    for (int o=32;o>0;o>>=1) m = fmaxf(m, __shfl_xor(m, o, 64));
    float e[8]; float s = 0.f;
    #pragma unroll
    for (int i=0;i<8;++i){ e[i] = expf(v[i]-m); s += e[i]; }
    #pragma unroll
    for (int o=32;o>0;o>>=1) s += __shfl_xor(s, o, 64);
    float lns = logf(s);
    float pl = 0.f;
    #pragma unroll
    for (int i=0;i<8;++i){ float p = e[i]/s; pl += p*((v[i]-m) - lns); }
    #pragma unroll
    for (int o=32;o>0;o>>=1) pl += __shfl_xor(pl, o, 64);
    int idx = action[b*3 + 0];
    if (t == (idx & 63)){
      float pe = 0.f;
      #pragma unroll
      for (int i=0;i<8;++i) if ((idx>>6)==i) pe = e[i];
      out[b*3 + 0] = pe / s;
    }
    if (t == 0) HendSh = -pl;
  }
  __syncthreads();
  float ab = bb1[t], as_ = bs1[t];
  #pragma unroll 4
  for (int k=0;k<128;++k){ float svk = sv[k]; ab += svk*bf2f(Wc[WOF_WB1 + k*cD + t]); as_ += svk*bf2f(Wc[WOF_WS1 + k*cD + t]); }
  #pragma unroll 4
  for (int k=0;k<128;++k) ab += ev[k]*bf2f(Wc[WOF_WB1 + (128+k)*cD + t]);
  float hb = fmaxf(ab,0.f), hs = fmaxf(as_,0.f);
  float r0 = hb*bf2f(Wc[WOF_WB2 + t*3+0]);
  float r1 = hb*bf2f(Wc[WOF_WB2 + t*3+1]);
  float r2 = hb*bf2f(Wc[WOF_WB2 + t*3+2]);
  float r3 = hs*bf2f(Wc[WOF_WS2 + t*2+0]);
  float r4 = hs*bf2f(Wc[WOF_WS2 + t*2+1]);
  #pragma unroll
  for (int o=32;o>0;o>>=1){
    r0 += __shfl_xor(r0,o,64); r1 += __shfl_xor(r1,o,64); r2 += __shfl_xor(r2,o,64);
    r3 += __shfl_xor(r3,o,64); r4 += __shfl_xor(r4,o,64);
  }
  if ((t&63)==0){ int wid=t>>6; red5[0][wid]=r0; red5[1][wid]=r1; red5[2][wid]=r2; red5[3][wid]=r3; red5[4][wid]=r4; }
  __syncthreads();
  if (t==0){
    out[128 + b] = redq[0] + redq[1] + bq2[0];
    auto xlx = [](float p){ return p > 0.f ? p*logf(p) : 0.f; };
    float bl0=red5[0][0]+red5[0][1], bl1=red5[1][0]+red5[1][1], bl2=red5[2][0]+red5[2][1];
    float sl0=red5[3][0]+red5[3][1], sl1=red5[4][0]+red5[4][1];
    float m = fmaxf(fmaxf(bl0,bl1),bl2);
    float e0=expf(bl0-m), e1=expf(bl1-m), e2=expf(bl2-m); float S=e0+e1+e2;
    float p0=e0/S, p1=e1/S, p2=e2/S;
    float Hb = -(xlx(p0) + xlx(p1) + xlx(p2));
    int a1 = action[b*3+1];
    out[b*3+1] = (a1==0)?p0:((a1==1)?p1:p2);
    float ms = fmaxf(sl0,sl1);
    float f0=expf(sl0-ms), f1=expf(sl1-ms); float T=f0+f1;
    float q0=f0/T, q1=f1/T;
    float Hs = -(xlx(q0) + xlx(q1));
    int a2 = action[b*3+2];
    out[b*3+2] = (a2==0)?q0:q1;
    out[96+b] = HendSh + Hb + Hs;
  }
}

// ================= launcher =================
extern "C" void kernel_launch(void* const* d_in, const int* in_sizes, int n_in,
                              void* d_out, int out_size, void* d_ws, size_t ws_size,
                              hipStream_t stream){
  const float* fatoms      = (const float*)d_in[0];
  const float* adj         = (const float*)d_in[1];
  const float* all_mask    = (const float*)d_in[2];
  const float* current_mask= (const float*)d_in[3];
  const float* prob_mask   = (const float*)d_in[4];
  const int*   focus       = (const int*)d_in[5];
  const int*   action      = (const int*)d_in[6];
  const float* actor_b     = (const float*)d_in[10];
  const float* critic_b    = (const float*)d_in[12];
  const float* be1         = (const float*)d_in[14];
  const float* bb1         = (const float*)d_in[17];
  const float* bs1         = (const float*)d_in[20];
  const float* bq1         = (const float*)d_in[23];
  const float* bq2         = (const float*)d_in[25];

  char* ws = (char*)d_ws;
  size_t o = 0;
  u16* adjT = (u16*)(ws + o);  o += (size_t)3*cB*cN*cN*2;        // 50.3 MB (written by k2f_l0)
  u16* WT   = (u16*)(ws + o);  o += (size_t)31*16384*2;          //  1.0 MB
  u16* hbuf = (u16*)(ws + o);  o += (size_t)2*2*cB*cN*cD*2;      // 16.8 MB (phase0=h0, phase1=hfin)
  u16* hwT0 = (u16*)(ws + o);  o += (size_t)2*3*cB*cD*cN*2;      // 25.2 MB
  u16* hwT1 = (u16*)(ws + o);  o += (size_t)2*3*cB*cD*cN*2;      // 25.2 MB
  u16* Wcan = (u16*)(ws + o);  o += (size_t)WTOTAL*2;
  float* part   = (float*)(ws + o); o += (size_t)cB*16*256*4;
  float* logits = (float*)(ws + o); o += (size_t)cB*cN*4;
  float* out = (float*)d_out;

  WPtrs wp;
  wp.p[0]=d_in[7];  wp.p[1]=d_in[8];  wp.p[2]=d_in[9];  wp.p[3]=d_in[11];
  wp.p[4]=d_in[13]; wp.p[5]=d_in[15]; wp.p[6]=d_in[16]; wp.p[7]=d_in[18];
  wp.p[8]=d_in[19]; wp.p[9]=d_in[21]; wp.p[10]=d_in[22]; wp.p[11]=d_in[24];

  canon_w<<<dim3((WTOTAL+255)/256), dim3(256), 0, stream>>>(wp, Wcan);
  prep_w<<<dim3(31), dim3(256), 0, stream>>>(Wcan, WT);
  emb<<<dim3(2*cB*cN), dim3(128), 0, stream>>>(fatoms, Wcan, hbuf);

  const size_t hstride = (size_t)2*cB*cN*cD;
  u16* hfin = hbuf + hstride;
  k1_hw<<<dim3(768), dim3(256), 0, stream>>>(WT, hbuf, actor_b, critic_b, hwT0, 0);
  k2f_l0<<<dim3(512), dim3(256), 0, stream>>>(adj, adjT, hwT0, hwT1, all_mask, WT, actor_b, critic_b);
  for (int l=1; l<cL; ++l){
    u16* win  = (l&1) ? hwT1 : hwT0;
    u16* wout = (l&1) ? hwT0 : hwT1;
    k2f_ln<<<dim3(512), dim3(256), 0, stream>>>(adjT, win, wout, all_mask, WT, actor_b, critic_b, hfin, l);
  }
  const u16* xa = hfin;
  const u16* xc = hfin + (size_t)cB*cN*cD;

  end_logits2<<<dim3(cB*4), dim3(256), 0, stream>>>(xa, WT, Wcan, focus, be1, prob_mask, logits);
  pool_part<<<dim3(cB*16), dim3(256), 0, stream>>>(xc, current_mask, part);
  heads_final<<<dim3(cB), dim3(128), 0, stream>>>(part, Wcan, bq1, bq2, logits, action, xa, focus, bb1, bs1, out);
}